// Round 5
// baseline (339.303 us; speedup 1.0000x reference)
//
#include <hip/hip_runtime.h>

typedef unsigned short u16;
typedef __attribute__((ext_vector_type(4))) float f32x4;
typedef __attribute__((ext_vector_type(8))) short bf16x8;

#define AS1 __attribute__((address_space(1)))
#define AS3 __attribute__((address_space(3)))

__device__ __forceinline__ float bf2f(u16 u) {
  union { unsigned int i; float f; } v; v.i = ((unsigned int)u) << 16; return v.f;
}
__device__ __forceinline__ u16 f2bf(float f) {
  union { float f; unsigned int i; } v; v.f = f;
  unsigned int r = v.i + 0x7fffu + ((v.i >> 16) & 1u);  // RNE
  return (u16)(r >> 16);
}
__device__ __forceinline__ void gload16(const void* g, void* l) {
  __builtin_amdgcn_global_load_lds((const AS1 unsigned int*)g, (AS3 unsigned int*)l, 16, 0, 0);
}

struct GemmDesc {
  const u16* A;      // [M][K] bf16, row stride lda
  const u16* Bt;     // [N][K] bf16, row stride ldb (B transposed)
  const float* Fadd; // optional f32 [M][N] addend (stride N)
  u16* D;            // optional bf16 out, row stride ldd
  u16* Dt;           // optional bf16 transposed out [N][M], row stride lddt
  float* Df;         // optional f32 out, row stride ldd
  int M, N, K, lda, ldb, ldd, lddt, tn, tiles;
  float scale;
};
struct GemmBatch { GemmDesc d[4]; int nd; };

// D = scale*(A @ Bt^T + Fadd), bf16 in, f32 acc. BMxBN tile, BK=64, 4 waves.
template<int BM, int BN>
__global__ __launch_bounds__(256) void gemm_bt(GemmBatch b) {
  const int nwg = gridDim.x;  // multiple of 8
  int t = ((blockIdx.x & 7) * (nwg >> 3)) + (blockIdx.x >> 3);
  int di = 0;
  while (di + 1 < b.nd && t >= b.d[di].tiles) { t -= b.d[di].tiles; ++di; }
  const GemmDesc d = b.d[di];
  const int tm = t / d.tn, tnn = t - tm * d.tn;
  const int m0 = tm * BM, n0 = tnn * BN;
  const int lane = threadIdx.x & 63;
  const int w = threadIdx.x >> 6;
  const int wm = w >> 1, wn = w & 1;
  constexpr int FM = BM / 32, FN = BN / 32;
  __shared__ __align__(16) u16 Asm[BM * 64];
  __shared__ __align__(16) u16 Bsm[BN * 64];
  f32x4 acc[FM][FN];
  #pragma unroll
  for (int i = 0; i < FM; ++i)
    #pragma unroll
    for (int j = 0; j < FN; ++j)
      acc[i][j] = (f32x4){0.f, 0.f, 0.f, 0.f};
  const int srow = lane >> 3, scol = (lane & 7) << 3;
  const int K = d.K;
  for (int k0 = 0; k0 < K; k0 += 64) {
    __syncthreads();
    #pragma unroll
    for (int c = w; c < BM / 8; c += 4)
      gload16(d.A + (size_t)(m0 + c * 8 + srow) * d.lda + k0 + scol, &Asm[c * 512]);
    #pragma unroll
    for (int c = w; c < BN / 8; c += 4)
      gload16(d.Bt + (size_t)(n0 + c * 8 + srow) * d.ldb + k0 + scol, &Bsm[c * 512]);
    __syncthreads();
    #pragma unroll
    for (int kk = 0; kk < 64; kk += 32) {
      bf16x8 af[FM], bfr[FN];
      #pragma unroll
      for (int i = 0; i < FM; ++i)
        af[i] = *(const bf16x8*)&Asm[(wm * (BM / 2) + i * 16 + (lane & 15)) * 64 + kk + ((lane >> 4) << 3)];
      #pragma unroll
      for (int j = 0; j < FN; ++j)
        bfr[j] = *(const bf16x8*)&Bsm[(wn * (BN / 2) + j * 16 + (lane & 15)) * 64 + kk + ((lane >> 4) << 3)];
      #pragma unroll
      for (int i = 0; i < FM; ++i)
        #pragma unroll
        for (int j = 0; j < FN; ++j)
          acc[i][j] = __builtin_amdgcn_mfma_f32_16x16x32_bf16(af[i], bfr[j], acc[i][j], 0, 0, 0);
    }
  }
  const int r4 = (lane >> 4) << 2;
  const int cc = lane & 15;
  #pragma unroll
  for (int i = 0; i < FM; ++i) {
    #pragma unroll
    for (int j = 0; j < FN; ++j) {
      const int row0 = m0 + wm * (BM / 2) + i * 16 + r4;
      const int col = n0 + wn * (BN / 2) + j * 16 + cc;
      float v[4];
      #pragma unroll
      for (int q = 0; q < 4; ++q) v[q] = acc[i][j][q];
      if (d.Fadd) {
        #pragma unroll
        for (int q = 0; q < 4; ++q) v[q] += d.Fadd[(size_t)(row0 + q) * d.N + col];
      }
      if (d.scale != 1.0f) {
        #pragma unroll
        for (int q = 0; q < 4; ++q) v[q] *= d.scale;
      }
      if (d.D) {
        #pragma unroll
        for (int q = 0; q < 4; ++q) d.D[(size_t)(row0 + q) * d.ldd + col] = f2bf(v[q]);
      }
      if (d.Df) {
        #pragma unroll
        for (int q = 0; q < 4; ++q) d.Df[(size_t)(row0 + q) * d.ldd + col] = v[q];
      }
      if (d.Dt) {
        ushort4 pk = make_ushort4(f2bf(v[0]), f2bf(v[1]), f2bf(v[2]), f2bf(v[3]));
        *(ushort4*)&d.Dt[(size_t)col * d.lddt + row0] = pk;
      }
    }
  }
}

// read f32 [R][C]; write straight bf16 [R][C] and transposed bf16 [C][R] (row stride ldt)
__global__ __launch_bounds__(256) void conv_both(const float* in, u16* outs, u16* outt, int R, int C, int ldt) {
  __shared__ float tile[64][65];
  int tiles_c = C >> 6;
  int tr = blockIdx.x / tiles_c;
  int tc = blockIdx.x - tr * tiles_c;
  int r0 = tr << 6, c0 = tc << 6;
  int lr = threadIdx.x >> 6, lc = threadIdx.x & 63;
  #pragma unroll
  for (int p = 0; p < 16; ++p) {
    int r = p * 4 + lr;
    float v = in[(size_t)(r0 + r) * C + c0 + lc];
    tile[r][lc] = v;
    outs[(size_t)(r0 + r) * C + c0 + lc] = f2bf(v);
  }
  __syncthreads();
  #pragma unroll
  for (int p = 0; p < 16; ++p) {
    int r = p * 4 + lr;
    outt[(size_t)(c0 + r) * ldt + r0 + lc] = f2bf(tile[lc][r]);
  }
}

// transposed-only bf16 convert: out [C][R]
__global__ __launch_bounds__(256) void conv_t(const float* in, u16* out, int R, int C) {
  __shared__ float tile[64][65];
  int tiles_c = C >> 6;
  int tr = blockIdx.x / tiles_c;
  int tc = blockIdx.x - tr * tiles_c;
  int r0 = tr << 6, c0 = tc << 6;
  int lr = threadIdx.x >> 6, lc = threadIdx.x & 63;
  #pragma unroll
  for (int p = 0; p < 16; ++p) {
    int r = p * 4 + lr;
    tile[r][lc] = in[(size_t)(r0 + r) * C + c0 + lc];
  }
  __syncthreads();
  #pragma unroll
  for (int p = 0; p < 16; ++p) {
    int r = p * 4 + lr;
    out[(size_t)(c0 + r) * R + r0 + lc] = f2bf(tile[lc][r]);
  }
}

// f32 -> bf16 straight (n4 = n/4)
__global__ __launch_bounds__(256) void conv_s(const float* in, u16* out, int n4) {
  int idx = blockIdx.x * 256 + threadIdx.x;
  int stride = gridDim.x * 256;
  for (int i = idx; i < n4; i += stride) {
    float4 f = ((const float4*)in)[i];
    ushort4 o = make_ushort4(f2bf(f.x), f2bf(f.y), f2bf(f.z), f2bf(f.w));
    ((ushort4*)out)[i] = o;
  }
}

// stage 1: partial[rc][j] = sum of 32 rows; grid = 16 rowchunks x 8 colblocks
__global__ __launch_bounds__(256) void colsum1(const float* Cm, float* partial, int cols) {
  int rc = blockIdx.x >> 3;
  int j = (blockIdx.x & 7) * 256 + threadIdx.x;
  float s = 0.f;
  #pragma unroll 8
  for (int i = 0; i < 32; ++i) s += Cm[(size_t)(rc * 32 + i) * cols + j];
  partial[(size_t)rc * cols + j] = s;
}
__global__ __launch_bounds__(256) void colsum2(const float* partial, float* v, int cols) {
  int j = blockIdx.x * 256 + threadIdx.x;
  float s = 0.f;
  #pragma unroll
  for (int rc = 0; rc < 16; ++rc) s += partial[(size_t)rc * cols + j];
  v[j] = s;
}

// tout = tadd + Mtx @ tmul ; Mtx bf16 [n][n] row-major
__global__ __launch_bounds__(256) void matvec_h(const u16* Mtx, const float* tmul,
                                                const float* tadd, float* tout, int n) {
  __shared__ float ts[2048];
  for (int i = threadIdx.x; i < n; i += 256) ts[i] = tmul[i];
  __syncthreads();
  int w = threadIdx.x >> 6, lane = threadIdx.x & 63;
  int row = blockIdx.x * 4 + w;
  float s = 0.f;
  for (int k0 = lane * 8; k0 < n; k0 += 512) {
    bf16x8 mv = *(const bf16x8*)&Mtx[(size_t)row * n + k0];
    #pragma unroll
    for (int e = 0; e < 8; ++e) s += bf2f((u16)mv[e]) * ts[k0 + e];
  }
  #pragma unroll
  for (int off = 32; off > 0; off >>= 1) s += __shfl_down(s, off);
  if (lane == 0) tout[row] = tadd[row] + s;
}

// u[row] = dot(Cm[row], t) ; Cm f32 [rows][n]
__global__ __launch_bounds__(256) void matvec_f32(const float* Cm, const float* t, float* u, int rows, int n) {
  __shared__ float ts[2048];
  for (int i = threadIdx.x; i < n; i += 256) ts[i] = t[i];
  __syncthreads();
  int w = threadIdx.x >> 6, lane = threadIdx.x & 63;
  int row = blockIdx.x * 4 + w;
  if (row >= rows) return;
  float s = 0.f;
  for (int k0 = lane * 4; k0 < n; k0 += 256) {
    float4 c4 = *(const float4*)&Cm[(size_t)row * n + k0];
    s += c4.x * ts[k0] + c4.y * ts[k0 + 1] + c4.z * ts[k0 + 2] + c4.w * ts[k0 + 3];
  }
  #pragma unroll
  for (int off = 32; off > 0; off >>= 1) s += __shfl_down(s, off);
  if (lane == 0) u[row] = s;
}

__global__ __launch_bounds__(256) void dhat_k(const float* DF, const float* u, float* out) {
  int idx = blockIdx.x * 256 + threadIdx.x;
  int i = idx >> 9;
  out[idx] = 0.5f * (1.0f - u[i]) * (1.0f / 512.0f) + 0.5f * DF[idx];
}

extern "C" void kernel_launch(void* const* d_in, const int* in_sizes, int n_in,
                              void* d_out, int out_size, void* d_ws, size_t ws_size,
                              hipStream_t stream) {
  (void)in_sizes; (void)n_in; (void)out_size; (void)ws_size;
  const float* Cf  = (const float*)d_in[0];  // [512][2048]
  const float* Af  = (const float*)d_in[1];  // [2048][2048]
  const float* AFf = (const float*)d_in[2];  // [2048][2048]
  const float* BFf = (const float*)d_in[3];  // [2048][512]
  const float* CFf = (const float*)d_in[4];  // [512][2048]
  const float* DFf = (const float*)d_in[5];  // [512][512]
  float* out = (float*)d_out;                // B_hat [2048][512] ++ D_hat [512][512]

  const size_t SLOT = 2048ull * 2048ull;     // elements (8 MiB as u16)
  char* ws = (char*)d_ws;
  auto slot = [&](int i) { return (u16*)(ws + (size_t)i * SLOT * 2); };
  // M = A^T, N = A_F
  u16* Mb   = slot(0);   // M straight
  u16* MbT  = slot(1);   // M^T = A straight
  u16* Nb   = slot(2);   // N straight
  u16* NbT  = slot(3);   // N^T straight
  u16* M2   = slot(4);   // M^2
  u16* N2   = slot(5);   // N^2
  u16* N2T  = slot(6);   // (N^2)^T
  u16* KP   = slot(7);   // [P0|P1|P2|P3] col-blocks of 512, P_k = M^k C^T
  u16* Rcat = slot(8);   // rows: [R0;R1;R2;R3], R_k = C_F N^k  [2048][2048]
  char* sk = ws + 9 * SLOT * 2;
  u16* Cb   = (u16*)sk;                      // C straight bf16 [512][2048] (= P0^T)
  u16* PT1  = Cb + 512 * 2048;               // P1^T [512][2048] ([Cb;PT1] stack is Bt for P2P3)
  u16* BFT  = PT1 + 512 * 2048;              // B_F^T [512][2048]
  u16* YHT  = BFT + 512 * 2048;              // (N^2 B_F)^T
  u16* YT   = YHT + 512 * 2048;              // (N^4 B_F)^T
  u16* WT   = YT + 512 * 2048;               // Wcat^T  [512][2048]
  u16* W2T  = WT + 512 * 2048;               // W'cat^T [512][2048]
  u16* ZT   = W2T + 512 * 2048;              // Z^T     [512][2048]
  u16* Z2T  = ZT + 512 * 2048;               // (M2 Z)^T [512][2048]
  float* Vf = (float*)(Z2T + 512 * 2048);    // V = KP@Wcat f32 [2048][512]
  float* part = Vf + 2048 * 512;
  float* vv = part + 16 * 2048;
  float* ta = vv + 4096;
  float* tb = ta + 4096;
  float* tc = tb + 4096;
  float* td = tc + 4096;
  float* uu = td + 4096;

  auto mk = [](const u16* A, int lda, const u16* Bt, int ldb, const float* Fadd,
               u16* D, u16* Dt, float* Df, int ldd, int lddt,
               int M, int N, int K, float scale, int bm, int bn) {
    GemmDesc g; g.A = A; g.Bt = Bt; g.Fadd = Fadd; g.D = D; g.Dt = Dt; g.Df = Df;
    g.M = M; g.N = N; g.K = K; g.lda = lda; g.ldb = ldb; g.ldd = ldd; g.lddt = lddt;
    g.tn = N / bn; g.tiles = (M / bm) * (N / bn); g.scale = scale; return g;
  };

  // ---- conversions ----
  conv_both<<<1024, 256, 0, stream>>>(Af, MbT, Mb, 2048, 2048, 2048);   // MbT=A, Mb=A^T=M
  conv_both<<<1024, 256, 0, stream>>>(AFf, Nb, NbT, 2048, 2048, 2048);  // Nb=N, NbT=N^T
  conv_both<<<256, 256, 0, stream>>>(Cf, Cb, KP, 512, 2048, 2048);      // Cb=C, KP col0 = C^T
  conv_s<<<1024, 256, 0, stream>>>(CFf, Rcat, (512 * 2048) / 4);        // Rcat rows 0..511 = R0 = C_F
  conv_t<<<256, 256, 0, stream>>>(BFf, BFT, 2048, 512);                 // BFT = B_F^T
  colsum1<<<128, 256, 0, stream>>>(Cf, part, 2048);
  colsum2<<<8, 256, 0, stream>>>(part, vv, 2048);
  matvec_h<<<512, 256, 0, stream>>>(Mb, vv, vv, ta, 2048);              // ta = (I+M)v

  // ---- G1: M2 = M@M | N2 = N@N (dual) | P1 = M@C^T (KP col1 + PT1) | R1^T = N^T@R0^T (Dt->Rcat row1) ----
  { GemmBatch gb{}; gb.nd = 4;
    gb.d[0] = mk(Mb, 2048, MbT, 2048, nullptr, M2, nullptr, nullptr, 2048, 2048, 2048, 2048, 2048, 1.f, 128, 128);
    gb.d[1] = mk(Nb, 2048, NbT, 2048, nullptr, N2, N2T, nullptr, 2048, 2048, 2048, 2048, 2048, 1.f, 128, 128);
    gb.d[2] = mk(Mb, 2048, Cb, 2048, nullptr, KP + 512, PT1, nullptr, 2048, 2048, 2048, 512, 2048, 1.f, 128, 128);
    gb.d[3] = mk(NbT, 2048, Rcat, 2048, nullptr, nullptr, Rcat + 512 * 2048, nullptr, 2048, 2048, 2048, 512, 2048, 1.f, 128, 128);
    gemm_bt<128, 128><<<640, 256, 0, stream>>>(gb); }
  // t-vector Horner with M2: td = sum_{k<8} M^k v
  matvec_h<<<512, 256, 0, stream>>>(M2, ta, ta, tb, 2048);
  matvec_h<<<512, 256, 0, stream>>>(M2, tb, ta, tc, 2048);
  matvec_h<<<512, 256, 0, stream>>>(M2, tc, ta, td, 2048);
  // ---- G2: [P2|P3]=M2@[P0|P1] | [R2;R3]=(N2^T@[R0;R1]^T)^T | YH=N2@B_F | Wlo=[R0;R1]@B_F ----
  { GemmBatch gb{}; gb.nd = 4;
    gb.d[0] = mk(M2, 2048, Cb, 2048, nullptr, KP + 1024, nullptr, nullptr, 2048, 2048, 2048, 1024, 2048, 1.f, 128, 128);
    gb.d[1] = mk(N2T, 2048, Rcat, 2048, nullptr, nullptr, Rcat + 1024 * 2048, nullptr, 2048, 2048, 2048, 1024, 2048, 1.f, 128, 128);
    gb.d[2] = mk(N2, 2048, BFT, 2048, nullptr, nullptr, YHT, nullptr, 2048, 2048, 2048, 512, 2048, 1.f, 128, 128);
    gb.d[3] = mk(Rcat, 2048, BFT, 2048, nullptr, nullptr, WT, nullptr, 2048, 2048, 1024, 512, 2048, 1.f, 128, 128);
    gemm_bt<128, 128><<<352, 256, 0, stream>>>(gb); }
  // ---- G3: Y = N2@YH (Dt->YT) | Whi = [R2;R3]@B_F (Dt->WT cols 1024..) — 128x64 ----
  { GemmBatch gb{}; gb.nd = 2;
    gb.d[0] = mk(N2, 2048, YHT, 2048, nullptr, nullptr, YT, nullptr, 2048, 2048, 2048, 512, 2048, 1.f, 128, 64);
    gb.d[1] = mk(Rcat + 1024 * 2048, 2048, BFT, 2048, nullptr, nullptr, WT + 1024, nullptr, 2048, 2048, 1024, 512, 2048, 1.f, 128, 64);
    gemm_bt<128, 64><<<192, 256, 0, stream>>>(gb); }
  // ---- G4: W'cat = Rcat@Y (Dt->W2T) | V = KP@Wcat (f32) — 128x64 ----
  { GemmBatch gb{}; gb.nd = 2;
    gb.d[0] = mk(Rcat, 2048, YT, 2048, nullptr, nullptr, W2T, nullptr, 2048, 2048, 2048, 512, 2048, 1.f, 128, 64);
    gb.d[1] = mk(KP, 2048, WT, 2048, nullptr, nullptr, nullptr, Vf, 512, 2048, 2048, 512, 2048, 1.f, 128, 64);
    gemm_bt<128, 64><<<256, 256, 0, stream>>>(gb); }
  // ---- G5: Z = KP@W'cat (Dt->ZT) ----
  { GemmBatch gb{}; gb.nd = 1;
    gb.d[0] = mk(KP, 2048, W2T, 2048, nullptr, nullptr, ZT, nullptr, 2048, 2048, 2048, 512, 2048, 1.f, 128, 64);
    gemm_bt<128, 64><<<128, 256, 0, stream>>>(gb); }
  // ---- G6: Z2 = M2@Z (Dt->Z2T) ----
  { GemmBatch gb{}; gb.nd = 1;
    gb.d[0] = mk(M2, 2048, ZT, 2048, nullptr, nullptr, Z2T, nullptr, 2048, 2048, 2048, 512, 2048, 1.f, 128, 64);
    gemm_bt<128, 64><<<128, 256, 0, stream>>>(gb); }
  // ---- G7: B_hat = -(V + M2@Z2) -> d_out f32 ----
  { GemmBatch gb{}; gb.nd = 1;
    gb.d[0] = mk(M2, 2048, Z2T, 2048, Vf, nullptr, nullptr, out, 512, 2048, 2048, 512, 2048, -1.f, 128, 64);
    gemm_bt<128, 64><<<128, 256, 0, stream>>>(gb); }
  // ---- D_hat ----
  matvec_f32<<<128, 256, 0, stream>>>(Cf, td, uu, 512, 2048);
  dhat_k<<<1024, 256, 0, stream>>>(DFf, uu, out + 2048 * 512);
}

// Round 6
// 285.855 us; speedup vs baseline: 1.1870x; 1.1870x over previous
//
#include <hip/hip_runtime.h>

typedef unsigned short u16;
typedef __attribute__((ext_vector_type(4))) float f32x4;
typedef __attribute__((ext_vector_type(8))) short bf16x8;

#define AS1 __attribute__((address_space(1)))
#define AS3 __attribute__((address_space(3)))

__device__ __forceinline__ float bf2f(u16 u) {
  union { unsigned int i; float f; } v; v.i = ((unsigned int)u) << 16; return v.f;
}
__device__ __forceinline__ u16 f2bf(float f) {
  union { float f; unsigned int i; } v; v.f = f;
  unsigned int r = v.i + 0x7fffu + ((v.i >> 16) & 1u);  // RNE
  return (u16)(r >> 16);
}
__device__ __forceinline__ void gload16(const void* g, void* l) {
  __builtin_amdgcn_global_load_lds((const AS1 unsigned int*)g, (AS3 unsigned int*)l, 16, 0, 0);
}

struct GemmDesc {
  const u16* A;      // [M][K] bf16, row stride lda
  const u16* Bt;     // [N][K] bf16, row stride ldb (B transposed)
  u16* D;            // optional bf16 out, row stride ldd
  u16* Dt;           // optional bf16 transposed out [N][M], row stride lddt
  float* Df;         // optional f32 out, row stride ldd
  int M, N, K, lda, ldb, ldd, lddt, tn, tiles;
  float scale;
};
struct GemmBatch { GemmDesc d[4]; int nd; };

// D = scale*(A @ Bt^T), bf16 in, f32 acc. BMxBN tile, BK=64, 4 waves (2x2).
template<int BM, int BN>
__global__ __launch_bounds__(256) void gemm_bt(GemmBatch b) {
  const int nwg = gridDim.x;  // multiple of 8
  int t = ((blockIdx.x & 7) * (nwg >> 3)) + (blockIdx.x >> 3);
  int di = 0;
  while (di + 1 < b.nd && t >= b.d[di].tiles) { t -= b.d[di].tiles; ++di; }
  const GemmDesc d = b.d[di];
  const int tm = t / d.tn, tnn = t - tm * d.tn;
  const int m0 = tm * BM, n0 = tnn * BN;
  const int lane = threadIdx.x & 63;
  const int w = threadIdx.x >> 6;
  const int wm = w >> 1, wn = w & 1;
  constexpr int FM = BM / 32, FN = BN / 32;
  __shared__ __align__(16) u16 Asm[BM * 64];
  __shared__ __align__(16) u16 Bsm[BN * 64];
  f32x4 acc[FM][FN];
  #pragma unroll
  for (int i = 0; i < FM; ++i)
    #pragma unroll
    for (int j = 0; j < FN; ++j)
      acc[i][j] = (f32x4){0.f, 0.f, 0.f, 0.f};
  const int srow = lane >> 3, scol = (lane & 7) << 3;
  const int K = d.K;
  for (int k0 = 0; k0 < K; k0 += 64) {
    __syncthreads();
    #pragma unroll
    for (int c = w; c < BM / 8; c += 4)
      gload16(d.A + (size_t)(m0 + c * 8 + srow) * d.lda + k0 + scol, &Asm[c * 512]);
    #pragma unroll
    for (int c = w; c < BN / 8; c += 4)
      gload16(d.Bt + (size_t)(n0 + c * 8 + srow) * d.ldb + k0 + scol, &Bsm[c * 512]);
    __syncthreads();
    #pragma unroll
    for (int kk = 0; kk < 64; kk += 32) {
      bf16x8 af[FM], bfr[FN];
      #pragma unroll
      for (int i = 0; i < FM; ++i)
        af[i] = *(const bf16x8*)&Asm[(wm * (BM / 2) + i * 16 + (lane & 15)) * 64 + kk + ((lane >> 4) << 3)];
      #pragma unroll
      for (int j = 0; j < FN; ++j)
        bfr[j] = *(const bf16x8*)&Bsm[(wn * (BN / 2) + j * 16 + (lane & 15)) * 64 + kk + ((lane >> 4) << 3)];
      #pragma unroll
      for (int i = 0; i < FM; ++i)
        #pragma unroll
        for (int j = 0; j < FN; ++j)
          acc[i][j] = __builtin_amdgcn_mfma_f32_16x16x32_bf16(af[i], bfr[j], acc[i][j], 0, 0, 0);
    }
  }
  const int r4 = (lane >> 4) << 2;
  const int cc = lane & 15;
  #pragma unroll
  for (int i = 0; i < FM; ++i) {
    #pragma unroll
    for (int j = 0; j < FN; ++j) {
      const int row0 = m0 + wm * (BM / 2) + i * 16 + r4;
      const int col = n0 + wn * (BN / 2) + j * 16 + cc;
      float v[4];
      #pragma unroll
      for (int q = 0; q < 4; ++q) v[q] = acc[i][j][q];
      if (d.scale != 1.0f) {
        #pragma unroll
        for (int q = 0; q < 4; ++q) v[q] *= d.scale;
      }
      if (d.D) {
        #pragma unroll
        for (int q = 0; q < 4; ++q) d.D[(size_t)(row0 + q) * d.ldd + col] = f2bf(v[q]);
      }
      if (d.Df) {
        #pragma unroll
        for (int q = 0; q < 4; ++q) d.Df[(size_t)(row0 + q) * d.ldd + col] = v[q];
      }
      if (d.Dt) {
        ushort4 pk = make_ushort4(f2bf(v[0]), f2bf(v[1]), f2bf(v[2]), f2bf(v[3]));
        *(ushort4*)&d.Dt[(size_t)col * d.lddt + row0] = pk;
      }
    }
  }
}

// read f32 [R][C]; write straight bf16 [R][C] and transposed bf16 [C][R] (row stride ldt)
__global__ __launch_bounds__(256) void conv_both(const float* in, u16* outs, u16* outt, int R, int C, int ldt) {
  __shared__ float tile[64][65];
  int tiles_c = C >> 6;
  int tr = blockIdx.x / tiles_c;
  int tc = blockIdx.x - tr * tiles_c;
  int r0 = tr << 6, c0 = tc << 6;
  int lr = threadIdx.x >> 6, lc = threadIdx.x & 63;
  #pragma unroll
  for (int p = 0; p < 16; ++p) {
    int r = p * 4 + lr;
    float v = in[(size_t)(r0 + r) * C + c0 + lc];
    tile[r][lc] = v;
    outs[(size_t)(r0 + r) * C + c0 + lc] = f2bf(v);
  }
  __syncthreads();
  #pragma unroll
  for (int p = 0; p < 16; ++p) {
    int r = p * 4 + lr;
    outt[(size_t)(c0 + r) * ldt + r0 + lc] = f2bf(tile[lc][r]);
  }
}

// transposed-only bf16 convert: out [C][R]
__global__ __launch_bounds__(256) void conv_t(const float* in, u16* out, int R, int C) {
  __shared__ float tile[64][65];
  int tiles_c = C >> 6;
  int tr = blockIdx.x / tiles_c;
  int tc = blockIdx.x - tr * tiles_c;
  int r0 = tr << 6, c0 = tc << 6;
  int lr = threadIdx.x >> 6, lc = threadIdx.x & 63;
  #pragma unroll
  for (int p = 0; p < 16; ++p) {
    int r = p * 4 + lr;
    tile[r][lc] = in[(size_t)(r0 + r) * C + c0 + lc];
  }
  __syncthreads();
  #pragma unroll
  for (int p = 0; p < 16; ++p) {
    int r = p * 4 + lr;
    out[(size_t)(c0 + r) * R + r0 + lc] = f2bf(tile[lc][r]);
  }
}

// f32 -> bf16 straight (n4 = n/4)
__global__ __launch_bounds__(256) void conv_s(const float* in, u16* out, int n4) {
  int idx = blockIdx.x * 256 + threadIdx.x;
  int stride = gridDim.x * 256;
  for (int i = idx; i < n4; i += stride) {
    float4 f = ((const float4*)in)[i];
    ushort4 o = make_ushort4(f2bf(f.x), f2bf(f.y), f2bf(f.z), f2bf(f.w));
    ((ushort4*)out)[i] = o;
  }
}

// t[row] = sum_j KP[row][j], KP bf16 [n][width]; grid = n/4 blocks
__global__ __launch_bounds__(256) void rowsum_bf(const u16* KP, float* t, int width) {
  int w = threadIdx.x >> 6, lane = threadIdx.x & 63;
  int row = blockIdx.x * 4 + w;
  float s = 0.f;
  for (int k0 = lane * 8; k0 < width; k0 += 512) {
    bf16x8 mv = *(const bf16x8*)&KP[(size_t)row * width + k0];
    #pragma unroll
    for (int e = 0; e < 8; ++e) s += bf2f((u16)mv[e]);
  }
  #pragma unroll
  for (int off = 32; off > 0; off >>= 1) s += __shfl_down(s, off);
  if (lane == 0) t[row] = s;
}

// fused: u[row] = dot(C_row, t); D_hat[row][:] = 0.5*(1-u)/512 + 0.5*DF[row][:]
__global__ __launch_bounds__(256) void matvec_dhat(const float* Cm, const float* t,
                                                   const float* DF, float* out) {
  __shared__ float ts[2048];
  for (int i = threadIdx.x; i < 2048; i += 256) ts[i] = t[i];
  __syncthreads();
  int w = threadIdx.x >> 6, lane = threadIdx.x & 63;
  int row = blockIdx.x * 4 + w;
  float s = 0.f;
  for (int k0 = lane * 4; k0 < 2048; k0 += 256) {
    float4 c4 = *(const float4*)&Cm[(size_t)row * 2048 + k0];
    s += c4.x * ts[k0] + c4.y * ts[k0 + 1] + c4.z * ts[k0 + 2] + c4.w * ts[k0 + 3];
  }
  #pragma unroll
  for (int off = 32; off > 0; off >>= 1) s += __shfl_down(s, off);
  s = __shfl(s, 0);
  float coef = 0.5f * (1.0f - s) * (1.0f / 512.0f);
  int j = lane * 8;
  #pragma unroll
  for (int e = 0; e < 8; ++e)
    out[(size_t)row * 512 + j + e] = coef + 0.5f * DF[(size_t)row * 512 + j + e];
}

extern "C" void kernel_launch(void* const* d_in, const int* in_sizes, int n_in,
                              void* d_out, int out_size, void* d_ws, size_t ws_size,
                              hipStream_t stream) {
  (void)in_sizes; (void)n_in; (void)out_size; (void)ws_size;
  const float* Cf  = (const float*)d_in[0];  // [512][2048]
  const float* Af  = (const float*)d_in[1];  // [2048][2048]
  const float* AFf = (const float*)d_in[2];  // [2048][2048]
  const float* BFf = (const float*)d_in[3];  // [2048][512]
  const float* CFf = (const float*)d_in[4];  // [512][2048]
  const float* DFf = (const float*)d_in[5];  // [512][512]
  float* out = (float*)d_out;                // B_hat [2048][512] ++ D_hat [512][512]

  const size_t NN = 2048ull * 2048ull;
  char* ws = (char*)d_ws;
  u16* Mb    = (u16*)ws;                 // M = A^T straight
  u16* MbT   = Mb + NN;                  // M^T = A straight
  u16* Nb    = MbT + NN;                 // N = A_F straight
  u16* NbT   = Nb + NN;                  // N^T straight
  u16* M2    = NbT + NN;                 // M^2
  u16* N2    = M2 + NN;                  // N^2
  u16* KP    = N2 + NN;                  // [P0|P1|...|P5]  [2048][3072], P_k = M^k C^T
  u16* KPT   = KP + 2048ull * 3072;      // [P0^T;P1^T;P2^T;P3^T] = [C; ...] [2048][2048]
  u16* EcatT = KPT + NN;                 // [e0^T;...;e5^T]  [3072][2048], e_k = N^k B_F
  u16* WB    = EcatT + 3072ull * 2048;   // WB[j][512k+r] = w_k[r][j]  [512][3072]
  u16* CFb   = WB + 512ull * 3072;       // C_F straight bf16 [512][2048]
  float* tv  = (float*)(CFb + 512ull * 2048);  // t [2048] f32

  auto mk = [](const u16* A, int lda, const u16* Bt, int ldb,
               u16* D, u16* Dt, float* Df, int ldd, int lddt,
               int M, int N, int K, float scale, int bm, int bn) {
    GemmDesc g; g.A = A; g.Bt = Bt; g.D = D; g.Dt = Dt; g.Df = Df;
    g.M = M; g.N = N; g.K = K; g.lda = lda; g.ldb = ldb; g.ldd = ldd; g.lddt = lddt;
    g.tn = N / bn; g.tiles = (M / bm) * (N / bn); g.scale = scale; return g;
  };

  // ---- conversions ----
  conv_both<<<1024, 256, 0, stream>>>(Af, MbT, Mb, 2048, 2048, 2048);   // MbT=A, Mb=A^T=M
  conv_both<<<1024, 256, 0, stream>>>(AFf, Nb, NbT, 2048, 2048, 2048);  // Nb=N, NbT=N^T
  conv_both<<<256, 256, 0, stream>>>(Cf, KPT, KP, 512, 2048, 3072);     // KPT rows0-511 = C (=P0^T); KP col-block0 = C^T
  conv_t<<<256, 256, 0, stream>>>(BFf, EcatT, 2048, 512);               // EcatT rows0-511 = B_F^T (=e0^T)
  conv_s<<<512, 256, 0, stream>>>(CFf, CFb, (512 * 2048) / 4);          // CFb = C_F

  // ---- G1: M2 = M@M | N2 = N@N | P1 = M@P0 (D->KP col1, Dt->KPT rows512+) | e1 = N@e0 (Dt->EcatT rows512+) ----
  { GemmBatch gb{}; gb.nd = 4;
    gb.d[0] = mk(Mb, 2048, MbT, 2048, M2, nullptr, nullptr, 2048, 0, 2048, 2048, 2048, 1.f, 128, 128);
    gb.d[1] = mk(Nb, 2048, NbT, 2048, N2, nullptr, nullptr, 2048, 0, 2048, 2048, 2048, 1.f, 128, 128);
    gb.d[2] = mk(Mb, 2048, KPT, 2048, KP + 512, KPT + 512 * 2048, nullptr, 3072, 2048, 2048, 512, 2048, 1.f, 128, 128);
    gb.d[3] = mk(Nb, 2048, EcatT, 2048, nullptr, EcatT + 512 * 2048, nullptr, 0, 2048, 2048, 512, 2048, 1.f, 128, 128);
    gemm_bt<128, 128><<<640, 256, 0, stream>>>(gb); }

  // ---- G2: [P2|P3]=M2@[P0|P1] (D->KP col2-3, Dt->KPT rows1024+) | [e2|e3]=N2@[e0|e1] (Dt) | w0 | w1 ----
  { GemmBatch gb{}; gb.nd = 4;
    gb.d[0] = mk(M2, 2048, KPT, 2048, KP + 1024, KPT + 1024 * 2048, nullptr, 3072, 2048, 2048, 1024, 2048, 1.f, 128, 128);
    gb.d[1] = mk(N2, 2048, EcatT, 2048, nullptr, EcatT + 1024 * 2048, nullptr, 0, 2048, 2048, 1024, 2048, 1.f, 128, 128);
    gb.d[2] = mk(CFb, 2048, EcatT, 2048, nullptr, WB, nullptr, 0, 3072, 512, 512, 2048, 1.f, 128, 128);
    gb.d[3] = mk(CFb, 2048, EcatT + 512 * 2048, 2048, nullptr, WB + 512, nullptr, 0, 3072, 512, 512, 2048, 1.f, 128, 128);
    gemm_bt<128, 128><<<288, 256, 0, stream>>>(gb); }

  // ---- G3: [P4|P5]=M2@[P2|P3] (D->KP col4-5) | [e4|e5]=N2@[e2|e3] (Dt) | w2 | w3 ----
  { GemmBatch gb{}; gb.nd = 4;
    gb.d[0] = mk(M2, 2048, KPT + 1024 * 2048, 2048, KP + 2048, nullptr, nullptr, 3072, 0, 2048, 1024, 2048, 1.f, 128, 128);
    gb.d[1] = mk(N2, 2048, EcatT + 1024 * 2048, 2048, nullptr, EcatT + 2048 * 2048, nullptr, 0, 2048, 2048, 1024, 2048, 1.f, 128, 128);
    gb.d[2] = mk(CFb, 2048, EcatT + 1024 * 2048, 2048, nullptr, WB + 1024, nullptr, 0, 3072, 512, 512, 2048, 1.f, 128, 128);
    gb.d[3] = mk(CFb, 2048, EcatT + 1536 * 2048, 2048, nullptr, WB + 1536, nullptr, 0, 3072, 512, 512, 2048, 1.f, 128, 128);
    gemm_bt<128, 128><<<288, 256, 0, stream>>>(gb); }

  // ---- G4: w4 | w5 ----
  { GemmBatch gb{}; gb.nd = 2;
    gb.d[0] = mk(CFb, 2048, EcatT + 2048 * 2048, 2048, nullptr, WB + 2048, nullptr, 0, 3072, 512, 512, 2048, 1.f, 128, 128);
    gb.d[1] = mk(CFb, 2048, EcatT + 2560 * 2048, 2048, nullptr, WB + 2560, nullptr, 0, 3072, 512, 512, 2048, 1.f, 128, 128);
    gemm_bt<128, 128><<<32, 256, 0, stream>>>(gb); }

  // ---- G5: B_hat = -(KP6 @ WB^T) -> d_out f32 ; K=3072 ----
  { GemmBatch gb{}; gb.nd = 1;
    gb.d[0] = mk(KP, 3072, WB, 3072, nullptr, nullptr, out, 512, 0, 2048, 512, 3072, -1.f, 128, 64);
    gemm_bt<128, 64><<<128, 256, 0, stream>>>(gb); }

  // ---- D_hat: t = rowsum(KP6) = sum_{k<6} M^k C^T 1 ; u = C t ; D_hat fused ----
  rowsum_bf<<<512, 256, 0, stream>>>(KP, tv, 3072);
  matvec_dhat<<<128, 256, 0, stream>>>(Cf, tv, DFf, out + 2048 * 512);
}

// Round 7
// 263.642 us; speedup vs baseline: 1.2870x; 1.0843x over previous
//
#include <hip/hip_runtime.h>

typedef unsigned short u16;
typedef __attribute__((ext_vector_type(4))) float f32x4;
typedef __attribute__((ext_vector_type(8))) short bf16x8;

#define AS1 __attribute__((address_space(1)))
#define AS3 __attribute__((address_space(3)))

__device__ __forceinline__ float bf2f(u16 u) {
  union { unsigned int i; float f; } v; v.i = ((unsigned int)u) << 16; return v.f;
}
__device__ __forceinline__ u16 f2bf(float f) {
  union { float f; unsigned int i; } v; v.f = f;
  unsigned int r = v.i + 0x7fffu + ((v.i >> 16) & 1u);  // RNE
  return (u16)(r >> 16);
}
__device__ __forceinline__ void gload16(const void* g, void* l) {
  __builtin_amdgcn_global_load_lds((const AS1 unsigned int*)g, (AS3 unsigned int*)l, 16, 0, 0);
}

struct GemmDesc {
  const u16* A;      // [M][K] bf16, row stride lda
  const u16* Bt;     // [N][K] bf16, row stride ldb (B transposed)
  u16* D;            // optional bf16 out, row stride ldd
  u16* Dt;           // optional bf16 transposed out [N][M], row stride lddt
  float* Df;         // optional f32 out, row stride ldd
  int M, N, K, lda, ldb, ldd, lddt, tn, tiles;
  float scale;
};
struct GemmBatch { GemmDesc d[4]; int nd; };

// ---------- epilogue shared by both kernels ----------
template<int BM, int BN, int FM, int FN>
__device__ __forceinline__ void epilogue(const GemmDesc& d, f32x4 (&acc)[FM][FN],
                                         int m0, int n0, int wm, int wn, int lane) {
  const int r4 = (lane >> 4) << 2;
  const int cc = lane & 15;
  #pragma unroll
  for (int i = 0; i < FM; ++i) {
    #pragma unroll
    for (int j = 0; j < FN; ++j) {
      const int row0 = m0 + wm * (BM / 2) + i * 16 + r4;
      const int col = n0 + wn * (BN / 2) + j * 16 + cc;
      float v[4];
      #pragma unroll
      for (int q = 0; q < 4; ++q) v[q] = acc[i][j][q];
      if (d.scale != 1.0f) {
        #pragma unroll
        for (int q = 0; q < 4; ++q) v[q] *= d.scale;
      }
      if (d.D) {
        #pragma unroll
        for (int q = 0; q < 4; ++q) d.D[(size_t)(row0 + q) * d.ldd + col] = f2bf(v[q]);
      }
      if (d.Df) {
        #pragma unroll
        for (int q = 0; q < 4; ++q) d.Df[(size_t)(row0 + q) * d.ldd + col] = v[q];
      }
      if (d.Dt) {
        ushort4 pk = make_ushort4(f2bf(v[0]), f2bf(v[1]), f2bf(v[2]), f2bf(v[3]));
        *(ushort4*)&d.Dt[(size_t)col * d.lddt + row0] = pk;
      }
    }
  }
}

// ---------- serial 2-barrier kernel (proven; used for the high-TLP G1) ----------
template<int BM, int BN>
__global__ __launch_bounds__(256) void gemm_bt(GemmBatch b) {
  const int nwg = gridDim.x;  // multiple of 8
  int t = ((blockIdx.x & 7) * (nwg >> 3)) + (blockIdx.x >> 3);
  int di = 0;
  while (di + 1 < b.nd && t >= b.d[di].tiles) { t -= b.d[di].tiles; ++di; }
  const GemmDesc d = b.d[di];
  const int tm = t / d.tn, tnn = t - tm * d.tn;
  const int m0 = tm * BM, n0 = tnn * BN;
  const int lane = threadIdx.x & 63;
  const int w = threadIdx.x >> 6;
  const int wm = w >> 1, wn = w & 1;
  constexpr int FM = BM / 32, FN = BN / 32;
  __shared__ __align__(16) u16 Asm[BM * 64];
  __shared__ __align__(16) u16 Bsm[BN * 64];
  f32x4 acc[FM][FN];
  #pragma unroll
  for (int i = 0; i < FM; ++i)
    #pragma unroll
    for (int j = 0; j < FN; ++j)
      acc[i][j] = (f32x4){0.f, 0.f, 0.f, 0.f};
  const int srow = lane >> 3, scol = (lane & 7) << 3;
  const int K = d.K;
  for (int k0 = 0; k0 < K; k0 += 64) {
    __syncthreads();
    #pragma unroll
    for (int c = w; c < BM / 8; c += 4)
      gload16(d.A + (size_t)(m0 + c * 8 + srow) * d.lda + k0 + scol, &Asm[c * 512]);
    #pragma unroll
    for (int c = w; c < BN / 8; c += 4)
      gload16(d.Bt + (size_t)(n0 + c * 8 + srow) * d.ldb + k0 + scol, &Bsm[c * 512]);
    __syncthreads();
    #pragma unroll
    for (int kk = 0; kk < 64; kk += 32) {
      bf16x8 af[FM], bfr[FN];
      #pragma unroll
      for (int i = 0; i < FM; ++i)
        af[i] = *(const bf16x8*)&Asm[(wm * (BM / 2) + i * 16 + (lane & 15)) * 64 + kk + ((lane >> 4) << 3)];
      #pragma unroll
      for (int j = 0; j < FN; ++j)
        bfr[j] = *(const bf16x8*)&Bsm[(wn * (BN / 2) + j * 16 + (lane & 15)) * 64 + kk + ((lane >> 4) << 3)];
      #pragma unroll
      for (int i = 0; i < FM; ++i)
        #pragma unroll
        for (int j = 0; j < FN; ++j)
          acc[i][j] = __builtin_amdgcn_mfma_f32_16x16x32_bf16(af[i], bfr[j], acc[i][j], 0, 0, 0);
    }
  }
  epilogue<BM, BN, FM, FN>(d, acc, m0, n0, wm, wn, lane);
}

// ---------- double-buffered pipelined kernel (counted vmcnt, raw barriers) ----------
// For low-TLP phases (<= ~2 blocks/CU of work): hides HBM latency via ILP.
template<int BM, int BN>
__global__ __launch_bounds__(256) void gemm_db(GemmBatch b) {
  const int nwg = gridDim.x;  // multiple of 8
  int t = ((blockIdx.x & 7) * (nwg >> 3)) + (blockIdx.x >> 3);
  int di = 0;
  while (di + 1 < b.nd && t >= b.d[di].tiles) { t -= b.d[di].tiles; ++di; }
  const GemmDesc d = b.d[di];
  const int tm = t / d.tn, tnn = t - tm * d.tn;
  const int m0 = tm * BM, n0 = tnn * BN;
  const int lane = threadIdx.x & 63;
  const int w = threadIdx.x >> 6;
  const int wm = w >> 1, wn = w & 1;
  constexpr int FM = BM / 32, FN = BN / 32;
  constexpr int HB = (BM + BN) * 64;       // u16 elems per half
  constexpr int L = (BM + BN) / 32;        // gload16 per wave per tile
  __shared__ __align__(16) u16 lds[2 * HB];
  f32x4 acc[FM][FN];
  #pragma unroll
  for (int i = 0; i < FM; ++i)
    #pragma unroll
    for (int j = 0; j < FN; ++j)
      acc[i][j] = (f32x4){0.f, 0.f, 0.f, 0.f};
  const int srow = lane >> 3, scol = (lane & 7) << 3;
  const int nt = d.K / 64;

  auto stagef = [&](int tt, int half) {
    const int k0 = tt * 64;
    u16* base = &lds[half * HB];
    #pragma unroll
    for (int c = w; c < BM / 8; c += 4)
      gload16(d.A + (size_t)(m0 + c * 8 + srow) * d.lda + k0 + scol, base + c * 512);
    #pragma unroll
    for (int c = w; c < BN / 8; c += 4)
      gload16(d.Bt + (size_t)(n0 + c * 8 + srow) * d.ldb + k0 + scol, base + BM * 64 + c * 512);
  };

  // prologue: 2-deep prefetch (K >= 128 always holds here)
  stagef(0, 0);
  stagef(1, 1);
  __builtin_amdgcn_sched_barrier(0);
  asm volatile("s_waitcnt vmcnt(%0)" :: "n"(L));  // tile0 landed (ours)
  __builtin_amdgcn_s_barrier();                   // everyone's tile0 landed
  __builtin_amdgcn_sched_barrier(0);

  for (int tt = 0; tt < nt; ++tt) {
    const u16* base = &lds[(tt & 1) * HB];
    #pragma unroll
    for (int kk = 0; kk < 64; kk += 32) {
      bf16x8 af[FM], bfr[FN];
      #pragma unroll
      for (int i = 0; i < FM; ++i)
        af[i] = *(const bf16x8*)&base[(wm * (BM / 2) + i * 16 + (lane & 15)) * 64 + kk + ((lane >> 4) << 3)];
      #pragma unroll
      for (int j = 0; j < FN; ++j)
        bfr[j] = *(const bf16x8*)&base[BM * 64 + (wn * (BN / 2) + j * 16 + (lane & 15)) * 64 + kk + ((lane >> 4) << 3)];
      #pragma unroll
      for (int i = 0; i < FM; ++i)
        #pragma unroll
        for (int j = 0; j < FN; ++j)
          acc[i][j] = __builtin_amdgcn_mfma_f32_16x16x32_bf16(af[i], bfr[j], acc[i][j], 0, 0, 0);
    }
    if (tt + 1 < nt) {
      __builtin_amdgcn_s_barrier();      // all waves done reading buf[tt&1]
      __builtin_amdgcn_sched_barrier(0);
      if (tt + 2 < nt) {
        stagef(tt + 2, tt & 1);          // refill freed buffer; loads fly across barrier
        __builtin_amdgcn_sched_barrier(0);
        asm volatile("s_waitcnt vmcnt(%0)" :: "n"(L));  // tile tt+1 landed; tt+2 in flight
      } else {
        asm volatile("s_waitcnt vmcnt(0)");
      }
      __builtin_amdgcn_s_barrier();      // everyone's tile tt+1 landed
      __builtin_amdgcn_sched_barrier(0);
    }
  }
  epilogue<BM, BN, FM, FN>(d, acc, m0, n0, wm, wn, lane);
}

// read f32 [R][C]; write straight bf16 [R][C] and transposed bf16 [C][R] (row stride ldt)
__global__ __launch_bounds__(256) void conv_both(const float* in, u16* outs, u16* outt, int R, int C, int ldt) {
  __shared__ float tile[64][65];
  int tiles_c = C >> 6;
  int tr = blockIdx.x / tiles_c;
  int tc = blockIdx.x - tr * tiles_c;
  int r0 = tr << 6, c0 = tc << 6;
  int lr = threadIdx.x >> 6, lc = threadIdx.x & 63;
  #pragma unroll
  for (int p = 0; p < 16; ++p) {
    int r = p * 4 + lr;
    float v = in[(size_t)(r0 + r) * C + c0 + lc];
    tile[r][lc] = v;
    outs[(size_t)(r0 + r) * C + c0 + lc] = f2bf(v);
  }
  __syncthreads();
  #pragma unroll
  for (int p = 0; p < 16; ++p) {
    int r = p * 4 + lr;
    outt[(size_t)(c0 + r) * ldt + r0 + lc] = f2bf(tile[lc][r]);
  }
}

// transposed-only bf16 convert: out [C][R]
__global__ __launch_bounds__(256) void conv_t(const float* in, u16* out, int R, int C) {
  __shared__ float tile[64][65];
  int tiles_c = C >> 6;
  int tr = blockIdx.x / tiles_c;
  int tc = blockIdx.x - tr * tiles_c;
  int r0 = tr << 6, c0 = tc << 6;
  int lr = threadIdx.x >> 6, lc = threadIdx.x & 63;
  #pragma unroll
  for (int p = 0; p < 16; ++p) {
    int r = p * 4 + lr;
    tile[r][lc] = in[(size_t)(r0 + r) * C + c0 + lc];
  }
  __syncthreads();
  #pragma unroll
  for (int p = 0; p < 16; ++p) {
    int r = p * 4 + lr;
    out[(size_t)(c0 + r) * R + r0 + lc] = f2bf(tile[lc][r]);
  }
}

// f32 -> bf16 straight (n4 = n/4)
__global__ __launch_bounds__(256) void conv_s(const float* in, u16* out, int n4) {
  int idx = blockIdx.x * 256 + threadIdx.x;
  int stride = gridDim.x * 256;
  for (int i = idx; i < n4; i += stride) {
    float4 f = ((const float4*)in)[i];
    ushort4 o = make_ushort4(f2bf(f.x), f2bf(f.y), f2bf(f.z), f2bf(f.w));
    ((ushort4*)out)[i] = o;
  }
}

// t[row] = sum_j KP[row][j], KP bf16 [n][width]; grid = n/4 blocks
__global__ __launch_bounds__(256) void rowsum_bf(const u16* KP, float* t, int width) {
  int w = threadIdx.x >> 6, lane = threadIdx.x & 63;
  int row = blockIdx.x * 4 + w;
  float s = 0.f;
  for (int k0 = lane * 8; k0 < width; k0 += 512) {
    bf16x8 mv = *(const bf16x8*)&KP[(size_t)row * width + k0];
    #pragma unroll
    for (int e = 0; e < 8; ++e) s += bf2f((u16)mv[e]);
  }
  #pragma unroll
  for (int off = 32; off > 0; off >>= 1) s += __shfl_down(s, off);
  if (lane == 0) t[row] = s;
}

// fused: u[row] = dot(C_row, t); D_hat[row][:] = 0.5*(1-u)/512 + 0.5*DF[row][:]
__global__ __launch_bounds__(256) void matvec_dhat(const float* Cm, const float* t,
                                                   const float* DF, float* out) {
  __shared__ float ts[2048];
  for (int i = threadIdx.x; i < 2048; i += 256) ts[i] = t[i];
  __syncthreads();
  int w = threadIdx.x >> 6, lane = threadIdx.x & 63;
  int row = blockIdx.x * 4 + w;
  float s = 0.f;
  for (int k0 = lane * 4; k0 < 2048; k0 += 256) {
    float4 c4 = *(const float4*)&Cm[(size_t)row * 2048 + k0];
    s += c4.x * ts[k0] + c4.y * ts[k0 + 1] + c4.z * ts[k0 + 2] + c4.w * ts[k0 + 3];
  }
  #pragma unroll
  for (int off = 32; off > 0; off >>= 1) s += __shfl_down(s, off);
  s = __shfl(s, 0);
  float coef = 0.5f * (1.0f - s) * (1.0f / 512.0f);
  int j = lane * 8;
  #pragma unroll
  for (int e = 0; e < 8; ++e)
    out[(size_t)row * 512 + j + e] = coef + 0.5f * DF[(size_t)row * 512 + j + e];
}

extern "C" void kernel_launch(void* const* d_in, const int* in_sizes, int n_in,
                              void* d_out, int out_size, void* d_ws, size_t ws_size,
                              hipStream_t stream) {
  (void)in_sizes; (void)n_in; (void)out_size; (void)ws_size;
  const float* Cf  = (const float*)d_in[0];  // [512][2048]
  const float* Af  = (const float*)d_in[1];  // [2048][2048]
  const float* AFf = (const float*)d_in[2];  // [2048][2048]
  const float* BFf = (const float*)d_in[3];  // [2048][512]
  const float* CFf = (const float*)d_in[4];  // [512][2048]
  const float* DFf = (const float*)d_in[5];  // [512][512]
  float* out = (float*)d_out;                // B_hat [2048][512] ++ D_hat [512][512]

  const size_t NN = 2048ull * 2048ull;
  char* ws = (char*)d_ws;
  u16* Mb    = (u16*)ws;                 // M = A^T straight
  u16* MbT   = Mb + NN;                  // M^T = A straight
  u16* Nb    = MbT + NN;                 // N = A_F straight
  u16* NbT   = Nb + NN;                  // N^T straight
  u16* M2    = NbT + NN;                 // M^2
  u16* N2    = M2 + NN;                  // N^2
  u16* KP    = N2 + NN;                  // [P0|P1|...|P5]  [2048][3072], P_k = M^k C^T
  u16* KPT   = KP + 2048ull * 3072;      // [P0^T;P1^T;P2^T;P3^T] [2048][2048]
  u16* EcatT = KPT + NN;                 // [e0^T;...;e5^T]  [3072][2048], e_k = N^k B_F
  u16* WB    = EcatT + 3072ull * 2048;   // WB[j][512k+r] = w_k[r][j]  [512][3072]
  u16* CFb   = WB + 512ull * 3072;       // C_F straight bf16 [512][2048]
  float* tv  = (float*)(CFb + 512ull * 2048);  // t [2048] f32

  auto mk = [](const u16* A, int lda, const u16* Bt, int ldb,
               u16* D, u16* Dt, float* Df, int ldd, int lddt,
               int M, int N, int K, float scale, int bm, int bn) {
    GemmDesc g; g.A = A; g.Bt = Bt; g.D = D; g.Dt = Dt; g.Df = Df;
    g.M = M; g.N = N; g.K = K; g.lda = lda; g.ldb = ldb; g.ldd = ldd; g.lddt = lddt;
    g.tn = N / bn; g.tiles = (M / bm) * (N / bn); g.scale = scale; return g;
  };

  // ---- conversions ----
  conv_both<<<1024, 256, 0, stream>>>(Af, MbT, Mb, 2048, 2048, 2048);   // MbT=A, Mb=A^T=M
  conv_both<<<1024, 256, 0, stream>>>(AFf, Nb, NbT, 2048, 2048, 2048);  // Nb=N, NbT=N^T
  conv_both<<<256, 256, 0, stream>>>(Cf, KPT, KP, 512, 2048, 3072);     // KPT rows0-511 = C; KP col-block0 = C^T
  conv_t<<<256, 256, 0, stream>>>(BFf, EcatT, 2048, 512);               // EcatT rows0-511 = B_F^T (=e0^T)
  conv_s<<<512, 256, 0, stream>>>(CFf, CFb, (512 * 2048) / 4);          // CFb = C_F

  // ---- G1 (serial kernel, high TLP): M2 = M@M | N2 = N@N | P1 = M@P0 | e1 = N@e0 ----
  { GemmBatch gb{}; gb.nd = 4;
    gb.d[0] = mk(Mb, 2048, MbT, 2048, M2, nullptr, nullptr, 2048, 0, 2048, 2048, 2048, 1.f, 128, 128);
    gb.d[1] = mk(Nb, 2048, NbT, 2048, N2, nullptr, nullptr, 2048, 0, 2048, 2048, 2048, 1.f, 128, 128);
    gb.d[2] = mk(Mb, 2048, KPT, 2048, KP + 512, KPT + 512 * 2048, nullptr, 3072, 2048, 2048, 512, 2048, 1.f, 128, 128);
    gb.d[3] = mk(Nb, 2048, EcatT, 2048, nullptr, EcatT + 512 * 2048, nullptr, 0, 2048, 2048, 512, 2048, 1.f, 128, 128);
    gemm_bt<128, 128><<<640, 256, 0, stream>>>(gb); }

  // ---- G2 (db): [P2|P3]=M2@[P0|P1] | [e2|e3]=N2@[e0|e1] | w0 | w1 ----
  { GemmBatch gb{}; gb.nd = 4;
    gb.d[0] = mk(M2, 2048, KPT, 2048, KP + 1024, KPT + 1024 * 2048, nullptr, 3072, 2048, 2048, 1024, 2048, 1.f, 128, 128);
    gb.d[1] = mk(N2, 2048, EcatT, 2048, nullptr, EcatT + 1024 * 2048, nullptr, 0, 2048, 2048, 1024, 2048, 1.f, 128, 128);
    gb.d[2] = mk(CFb, 2048, EcatT, 2048, nullptr, WB, nullptr, 0, 3072, 512, 512, 2048, 1.f, 128, 128);
    gb.d[3] = mk(CFb, 2048, EcatT + 512 * 2048, 2048, nullptr, WB + 512, nullptr, 0, 3072, 512, 512, 2048, 1.f, 128, 128);
    gemm_db<128, 128><<<288, 256, 0, stream>>>(gb); }

  // ---- G3 (db): [P4|P5]=M2@[P2|P3] | [e4|e5]=N2@[e2|e3] | w2 | w3 ----
  { GemmBatch gb{}; gb.nd = 4;
    gb.d[0] = mk(M2, 2048, KPT + 1024 * 2048, 2048, KP + 2048, nullptr, nullptr, 3072, 0, 2048, 1024, 2048, 1.f, 128, 128);
    gb.d[1] = mk(N2, 2048, EcatT + 1024 * 2048, 2048, nullptr, EcatT + 2048 * 2048, nullptr, 0, 2048, 2048, 1024, 2048, 1.f, 128, 128);
    gb.d[2] = mk(CFb, 2048, EcatT + 1024 * 2048, 2048, nullptr, WB + 1024, nullptr, 0, 3072, 512, 512, 2048, 1.f, 128, 128);
    gb.d[3] = mk(CFb, 2048, EcatT + 1536 * 2048, 2048, nullptr, WB + 1536, nullptr, 0, 3072, 512, 512, 2048, 1.f, 128, 128);
    gemm_db<128, 128><<<288, 256, 0, stream>>>(gb); }

  // ---- G4 (db): w4 | w5 ----
  { GemmBatch gb{}; gb.nd = 2;
    gb.d[0] = mk(CFb, 2048, EcatT + 2048 * 2048, 2048, nullptr, WB + 2048, nullptr, 0, 3072, 512, 512, 2048, 1.f, 128, 128);
    gb.d[1] = mk(CFb, 2048, EcatT + 2560 * 2048, 2048, nullptr, WB + 2560, nullptr, 0, 3072, 512, 512, 2048, 1.f, 128, 128);
    gemm_db<128, 128><<<32, 256, 0, stream>>>(gb); }

  // ---- G5 (db): B_hat = -(KP6 @ WB^T) -> d_out f32 ; K=3072 ----
  { GemmBatch gb{}; gb.nd = 1;
    gb.d[0] = mk(KP, 3072, WB, 3072, nullptr, nullptr, out, 512, 0, 2048, 512, 3072, -1.f, 128, 64);
    gemm_db<128, 64><<<128, 256, 0, stream>>>(gb); }

  // ---- D_hat: t = rowsum(KP6) ; u = C t ; D_hat fused ----
  rowsum_bf<<<512, 256, 0, stream>>>(KP, tv, 3072);
  matvec_dhat<<<128, 256, 0, stream>>>(Cf, tv, DFf, out + 2048 * 512);
}

// Round 8
// 230.771 us; speedup vs baseline: 1.4703x; 1.1424x over previous
//
#include <hip/hip_runtime.h>

typedef unsigned short u16;
typedef __attribute__((ext_vector_type(4))) float f32x4;
typedef __attribute__((ext_vector_type(8))) short bf16x8;

#define AS1 __attribute__((address_space(1)))
#define AS3 __attribute__((address_space(3)))

__device__ __forceinline__ float bf2f(u16 u) {
  union { unsigned int i; float f; } v; v.i = ((unsigned int)u) << 16; return v.f;
}
__device__ __forceinline__ u16 f2bf(float f) {
  union { float f; unsigned int i; } v; v.f = f;
  unsigned int r = v.i + 0x7fffu + ((v.i >> 16) & 1u);  // RNE
  return (u16)(r >> 16);
}
__device__ __forceinline__ void gload16(const void* g, void* l) {
  __builtin_amdgcn_global_load_lds((const AS1 unsigned int*)g, (AS3 unsigned int*)l, 16, 0, 0);
}

struct GemmDesc {
  const u16* A;      // [M][K] bf16, row stride lda
  const u16* Bt;     // [N][K] bf16, row stride ldb (B transposed)
  u16* D;            // optional bf16 out, row stride ldd
  u16* Dt;           // optional bf16 transposed out [N][M], row stride lddt
  float* Df;         // optional f32 out, row stride ldd
  int M, N, K, lda, ldb, ldd, lddt, tn, tiles;
  float scale;
};
struct GemmBatch { GemmDesc d[4]; int nd; };

template<int BM, int BN, int FM, int FN>
__device__ __forceinline__ void epilogue(const GemmDesc& d, f32x4 (&acc)[FM][FN],
                                         int m0, int n0, int wm, int wn, int lane) {
  const int r4 = (lane >> 4) << 2;
  const int cc = lane & 15;
  #pragma unroll
  for (int i = 0; i < FM; ++i) {
    #pragma unroll
    for (int j = 0; j < FN; ++j) {
      const int row0 = m0 + wm * (BM / 2) + i * 16 + r4;
      const int col = n0 + wn * (BN / 2) + j * 16 + cc;
      float v[4];
      #pragma unroll
      for (int q = 0; q < 4; ++q) v[q] = acc[i][j][q];
      if (d.scale != 1.0f) {
        #pragma unroll
        for (int q = 0; q < 4; ++q) v[q] *= d.scale;
      }
      if (d.D) {
        #pragma unroll
        for (int q = 0; q < 4; ++q) d.D[(size_t)(row0 + q) * d.ldd + col] = f2bf(v[q]);
      }
      if (d.Df) {
        #pragma unroll
        for (int q = 0; q < 4; ++q) d.Df[(size_t)(row0 + q) * d.ldd + col] = v[q];
      }
      if (d.Dt) {
        ushort4 pk = make_ushort4(f2bf(v[0]), f2bf(v[1]), f2bf(v[2]), f2bf(v[3]));
        *(ushort4*)&d.Dt[(size_t)col * d.lddt + row0] = pk;
      }
    }
  }
}

// ---------- double-buffered pipelined kernel with T2 XOR-swizzled LDS ----------
// LDS[r][c] holds global[r][c ^ ((r&7)<<3)]  (XOR on u16-col bits 3-5).
// Stage: linear LDS dest (gload16 requirement), pre-swizzled global source col.
// Read: col ^= ((row&7)<<3); row&7 == lane&7 in the fragment map -> 16-way
// bank conflict becomes 2-way (free).
template<int BM, int BN>
__global__ __launch_bounds__(256) void gemm_db(GemmBatch b) {
  const int nwg = gridDim.x;  // multiple of 8
  int t = ((blockIdx.x & 7) * (nwg >> 3)) + (blockIdx.x >> 3);
  int di = 0;
  while (di + 1 < b.nd && t >= b.d[di].tiles) { t -= b.d[di].tiles; ++di; }
  const GemmDesc d = b.d[di];
  const int tm = t / d.tn, tnn = t - tm * d.tn;
  const int m0 = tm * BM, n0 = tnn * BN;
  const int lane = threadIdx.x & 63;
  const int w = threadIdx.x >> 6;
  const int wm = w >> 1, wn = w & 1;
  constexpr int FM = BM / 32, FN = BN / 32;
  constexpr int HB = (BM + BN) * 64;       // u16 elems per half
  constexpr int L = (BM + BN) / 32;        // gload16 per wave per tile
  __shared__ __align__(16) u16 lds[2 * HB];
  f32x4 acc[FM][FN];
  #pragma unroll
  for (int i = 0; i < FM; ++i)
    #pragma unroll
    for (int j = 0; j < FN; ++j)
      acc[i][j] = (f32x4){0.f, 0.f, 0.f, 0.f};
  const int srow = lane >> 3;
  const int scolz = (((lane & 7) << 3) ^ (srow << 3));  // pre-swizzled source col
  const int rsw = (lane & 7) << 3;                      // read-side XOR constant
  const int nt = d.K / 64;

  auto stagef = [&](int tt, int half) {
    const int k0 = tt * 64;
    u16* base = &lds[half * HB];
    #pragma unroll
    for (int c = w; c < BM / 8; c += 4)
      gload16(d.A + (size_t)(m0 + c * 8 + srow) * d.lda + k0 + scolz, base + c * 512);
    #pragma unroll
    for (int c = w; c < BN / 8; c += 4)
      gload16(d.Bt + (size_t)(n0 + c * 8 + srow) * d.ldb + k0 + scolz, base + BM * 64 + c * 512);
  };

  // prologue: 2-deep prefetch (K >= 128 always holds here)
  stagef(0, 0);
  stagef(1, 1);
  __builtin_amdgcn_sched_barrier(0);
  asm volatile("s_waitcnt vmcnt(%0)" :: "n"(L));  // tile0 landed (ours)
  __builtin_amdgcn_s_barrier();                   // everyone's tile0 landed
  __builtin_amdgcn_sched_barrier(0);

  for (int tt = 0; tt < nt; ++tt) {
    const u16* base = &lds[(tt & 1) * HB];
    #pragma unroll
    for (int kk = 0; kk < 64; kk += 32) {
      const int cb = (kk + ((lane >> 4) << 3)) ^ rsw;  // swizzled col base
      bf16x8 af[FM], bfr[FN];
      #pragma unroll
      for (int i = 0; i < FM; ++i)
        af[i] = *(const bf16x8*)&base[(wm * (BM / 2) + i * 16 + (lane & 15)) * 64 + cb];
      #pragma unroll
      for (int j = 0; j < FN; ++j)
        bfr[j] = *(const bf16x8*)&base[BM * 64 + (wn * (BN / 2) + j * 16 + (lane & 15)) * 64 + cb];
      #pragma unroll
      for (int i = 0; i < FM; ++i)
        #pragma unroll
        for (int j = 0; j < FN; ++j)
          acc[i][j] = __builtin_amdgcn_mfma_f32_16x16x32_bf16(af[i], bfr[j], acc[i][j], 0, 0, 0);
    }
    if (tt + 1 < nt) {
      __builtin_amdgcn_s_barrier();      // all waves done reading buf[tt&1]
      __builtin_amdgcn_sched_barrier(0);
      if (tt + 2 < nt) {
        stagef(tt + 2, tt & 1);          // refill freed buffer; loads fly across barrier
        __builtin_amdgcn_sched_barrier(0);
        asm volatile("s_waitcnt vmcnt(%0)" :: "n"(L));  // tile tt+1 landed; tt+2 in flight
      } else {
        asm volatile("s_waitcnt vmcnt(0)");
      }
      __builtin_amdgcn_s_barrier();      // everyone's tile tt+1 landed
      __builtin_amdgcn_sched_barrier(0);
    }
  }
  epilogue<BM, BN, FM, FN>(d, acc, m0, n0, wm, wn, lane);
}

// read f32 [R][C]; write straight bf16 [R][C] and transposed bf16 [C][R] (row stride ldt)
__global__ __launch_bounds__(256) void conv_both(const float* in, u16* outs, u16* outt, int R, int C, int ldt) {
  __shared__ float tile[64][65];
  int tiles_c = C >> 6;
  int tr = blockIdx.x / tiles_c;
  int tc = blockIdx.x - tr * tiles_c;
  int r0 = tr << 6, c0 = tc << 6;
  int lr = threadIdx.x >> 6, lc = threadIdx.x & 63;
  #pragma unroll
  for (int p = 0; p < 16; ++p) {
    int r = p * 4 + lr;
    float v = in[(size_t)(r0 + r) * C + c0 + lc];
    tile[r][lc] = v;
    outs[(size_t)(r0 + r) * C + c0 + lc] = f2bf(v);
  }
  __syncthreads();
  #pragma unroll
  for (int p = 0; p < 16; ++p) {
    int r = p * 4 + lr;
    outt[(size_t)(c0 + r) * ldt + r0 + lc] = f2bf(tile[lc][r]);
  }
}

// transposed-only bf16 convert: out [C][R]
__global__ __launch_bounds__(256) void conv_t(const float* in, u16* out, int R, int C) {
  __shared__ float tile[64][65];
  int tiles_c = C >> 6;
  int tr = blockIdx.x / tiles_c;
  int tc = blockIdx.x - tr * tiles_c;
  int r0 = tr << 6, c0 = tc << 6;
  int lr = threadIdx.x >> 6, lc = threadIdx.x & 63;
  #pragma unroll
  for (int p = 0; p < 16; ++p) {
    int r = p * 4 + lr;
    tile[r][lc] = in[(size_t)(r0 + r) * C + c0 + lc];
  }
  __syncthreads();
  #pragma unroll
  for (int p = 0; p < 16; ++p) {
    int r = p * 4 + lr;
    out[(size_t)(c0 + r) * R + r0 + lc] = f2bf(tile[lc][r]);
  }
}

// f32 -> bf16 straight (n4 = n/4)
__global__ __launch_bounds__(256) void conv_s(const float* in, u16* out, int n4) {
  int idx = blockIdx.x * 256 + threadIdx.x;
  int stride = gridDim.x * 256;
  for (int i = idx; i < n4; i += stride) {
    float4 f = ((const float4*)in)[i];
    ushort4 o = make_ushort4(f2bf(f.x), f2bf(f.y), f2bf(f.z), f2bf(f.w));
    ((ushort4*)out)[i] = o;
  }
}

// t[row] = sum_j KP[row][j], KP bf16 [n][width]; grid = n/4 blocks
__global__ __launch_bounds__(256) void rowsum_bf(const u16* KP, float* t, int width) {
  int w = threadIdx.x >> 6, lane = threadIdx.x & 63;
  int row = blockIdx.x * 4 + w;
  float s = 0.f;
  for (int k0 = lane * 8; k0 < width; k0 += 512) {
    bf16x8 mv = *(const bf16x8*)&KP[(size_t)row * width + k0];
    #pragma unroll
    for (int e = 0; e < 8; ++e) s += bf2f((u16)mv[e]);
  }
  #pragma unroll
  for (int off = 32; off > 0; off >>= 1) s += __shfl_down(s, off);
  if (lane == 0) t[row] = s;
}

// fused: u[row] = dot(C_row, t); D_hat[row][:] = 0.5*(1-u)/512 + 0.5*DF[row][:]
__global__ __launch_bounds__(256) void matvec_dhat(const float* Cm, const float* t,
                                                   const float* DF, float* out) {
  __shared__ float ts[2048];
  for (int i = threadIdx.x; i < 2048; i += 256) ts[i] = t[i];
  __syncthreads();
  int w = threadIdx.x >> 6, lane = threadIdx.x & 63;
  int row = blockIdx.x * 4 + w;
  float s = 0.f;
  for (int k0 = lane * 4; k0 < 2048; k0 += 256) {
    float4 c4 = *(const float4*)&Cm[(size_t)row * 2048 + k0];
    s += c4.x * ts[k0] + c4.y * ts[k0 + 1] + c4.z * ts[k0 + 2] + c4.w * ts[k0 + 3];
  }
  #pragma unroll
  for (int off = 32; off > 0; off >>= 1) s += __shfl_down(s, off);
  s = __shfl(s, 0);
  float coef = 0.5f * (1.0f - s) * (1.0f / 512.0f);
  int j = lane * 8;
  #pragma unroll
  for (int e = 0; e < 8; ++e)
    out[(size_t)row * 512 + j + e] = coef + 0.5f * DF[(size_t)row * 512 + j + e];
}

extern "C" void kernel_launch(void* const* d_in, const int* in_sizes, int n_in,
                              void* d_out, int out_size, void* d_ws, size_t ws_size,
                              hipStream_t stream) {
  (void)in_sizes; (void)n_in; (void)out_size; (void)ws_size;
  const float* Cf  = (const float*)d_in[0];  // [512][2048]
  const float* Af  = (const float*)d_in[1];  // [2048][2048]
  const float* AFf = (const float*)d_in[2];  // [2048][2048]
  const float* BFf = (const float*)d_in[3];  // [2048][512]
  const float* CFf = (const float*)d_in[4];  // [512][2048]
  const float* DFf = (const float*)d_in[5];  // [512][512]
  float* out = (float*)d_out;                // B_hat [2048][512] ++ D_hat [512][512]

  const size_t NN = 2048ull * 2048ull;
  char* ws = (char*)d_ws;
  u16* Mb    = (u16*)ws;                 // M = A^T straight
  u16* MbT   = Mb + NN;                  // M^T = A straight
  u16* Nb    = MbT + NN;                 // N = A_F straight
  u16* NbT   = Nb + NN;                  // N^T straight
  u16* M2    = NbT + NN;                 // M^2
  u16* N2    = M2 + NN;                  // N^2
  u16* KP    = N2 + NN;                  // [P0|P1|...|P5]  [2048][3072], P_k = M^k C^T
  u16* KPT   = KP + 2048ull * 3072;      // [P0^T;P1^T;P2^T;P3^T] [2048][2048]
  u16* EcatT = KPT + NN;                 // [e0^T;...;e5^T]  [3072][2048], e_k = N^k B_F
  u16* WB    = EcatT + 3072ull * 2048;   // WB[j][512k+r] = w_k[r][j]  [512][3072]
  u16* CFb   = WB + 512ull * 3072;       // C_F straight bf16 [512][2048]
  float* tv  = (float*)(CFb + 512ull * 2048);  // t [2048] f32

  auto mk = [](const u16* A, int lda, const u16* Bt, int ldb,
               u16* D, u16* Dt, float* Df, int ldd, int lddt,
               int M, int N, int K, float scale, int bm, int bn) {
    GemmDesc g; g.A = A; g.Bt = Bt; g.D = D; g.Dt = Dt; g.Df = Df;
    g.M = M; g.N = N; g.K = K; g.lda = lda; g.ldb = ldb; g.ldd = ldd; g.lddt = lddt;
    g.tn = N / bn; g.tiles = (M / bm) * (N / bn); g.scale = scale; return g;
  };

  // ---- conversions ----
  conv_both<<<1024, 256, 0, stream>>>(Af, MbT, Mb, 2048, 2048, 2048);   // MbT=A, Mb=A^T=M
  conv_both<<<1024, 256, 0, stream>>>(AFf, Nb, NbT, 2048, 2048, 2048);  // Nb=N, NbT=N^T
  conv_both<<<256, 256, 0, stream>>>(Cf, KPT, KP, 512, 2048, 3072);     // KPT rows0-511 = C; KP col-block0 = C^T
  conv_t<<<256, 256, 0, stream>>>(BFf, EcatT, 2048, 512);               // EcatT rows0-511 = B_F^T (=e0^T)
  conv_s<<<512, 256, 0, stream>>>(CFf, CFb, (512 * 2048) / 4);          // CFb = C_F

  // ---- G1 (db+swz): M2 = M@M | N2 = N@N | P1 = M@P0 | e1 = N@e0 ----
  { GemmBatch gb{}; gb.nd = 4;
    gb.d[0] = mk(Mb, 2048, MbT, 2048, M2, nullptr, nullptr, 2048, 0, 2048, 2048, 2048, 1.f, 128, 128);
    gb.d[1] = mk(Nb, 2048, NbT, 2048, N2, nullptr, nullptr, 2048, 0, 2048, 2048, 2048, 1.f, 128, 128);
    gb.d[2] = mk(Mb, 2048, KPT, 2048, KP + 512, KPT + 512 * 2048, nullptr, 3072, 2048, 2048, 512, 2048, 1.f, 128, 128);
    gb.d[3] = mk(Nb, 2048, EcatT, 2048, nullptr, EcatT + 512 * 2048, nullptr, 0, 2048, 2048, 512, 2048, 1.f, 128, 128);
    gemm_db<128, 128><<<640, 256, 0, stream>>>(gb); }

  // ---- G2 (db+swz): [P2|P3]=M2@[P0|P1] | [e2|e3]=N2@[e0|e1] | w0 | w1 ----
  { GemmBatch gb{}; gb.nd = 4;
    gb.d[0] = mk(M2, 2048, KPT, 2048, KP + 1024, KPT + 1024 * 2048, nullptr, 3072, 2048, 2048, 1024, 2048, 1.f, 128, 128);
    gb.d[1] = mk(N2, 2048, EcatT, 2048, nullptr, EcatT + 1024 * 2048, nullptr, 0, 2048, 2048, 1024, 2048, 1.f, 128, 128);
    gb.d[2] = mk(CFb, 2048, EcatT, 2048, nullptr, WB, nullptr, 0, 3072, 512, 512, 2048, 1.f, 128, 128);
    gb.d[3] = mk(CFb, 2048, EcatT + 512 * 2048, 2048, nullptr, WB + 512, nullptr, 0, 3072, 512, 512, 2048, 1.f, 128, 128);
    gemm_db<128, 128><<<288, 256, 0, stream>>>(gb); }

  // ---- G3 (db+swz): [P4|P5]=M2@[P2|P3] | [e4|e5]=N2@[e2|e3] | w2 | w3 ----
  { GemmBatch gb{}; gb.nd = 4;
    gb.d[0] = mk(M2, 2048, KPT + 1024 * 2048, 2048, KP + 2048, nullptr, nullptr, 3072, 0, 2048, 1024, 2048, 1.f, 128, 128);
    gb.d[1] = mk(N2, 2048, EcatT + 1024 * 2048, 2048, nullptr, EcatT + 2048 * 2048, nullptr, 0, 2048, 2048, 1024, 2048, 1.f, 128, 128);
    gb.d[2] = mk(CFb, 2048, EcatT + 1024 * 2048, 2048, nullptr, WB + 1024, nullptr, 0, 3072, 512, 512, 2048, 1.f, 128, 128);
    gb.d[3] = mk(CFb, 2048, EcatT + 1536 * 2048, 2048, nullptr, WB + 1536, nullptr, 0, 3072, 512, 512, 2048, 1.f, 128, 128);
    gemm_db<128, 128><<<288, 256, 0, stream>>>(gb); }

  // ---- G4 (db+swz): w4 | w5 ----
  { GemmBatch gb{}; gb.nd = 2;
    gb.d[0] = mk(CFb, 2048, EcatT + 2048 * 2048, 2048, nullptr, WB + 2048, nullptr, 0, 3072, 512, 512, 2048, 1.f, 128, 128);
    gb.d[1] = mk(CFb, 2048, EcatT + 2560 * 2048, 2048, nullptr, WB + 2560, nullptr, 0, 3072, 512, 512, 2048, 1.f, 128, 128);
    gemm_db<128, 128><<<32, 256, 0, stream>>>(gb); }

  // ---- G5 (db+swz): B_hat = -(KP6 @ WB^T) -> d_out f32 ; K=3072 ----
  { GemmBatch gb{}; gb.nd = 1;
    gb.d[0] = mk(KP, 3072, WB, 3072, nullptr, nullptr, out, 512, 0, 2048, 512, 3072, -1.f, 128, 64);
    gemm_db<128, 64><<<128, 256, 0, stream>>>(gb); }

  // ---- D_hat: t = rowsum(KP6) ; u = C t ; D_hat fused ----
  rowsum_bf<<<512, 256, 0, stream>>>(KP, tv, 3072);
  matvec_dhat<<<128, 256, 0, stream>>>(Cf, tv, DFf, out + 2048 * 512);
}

// Round 9
// 140.145 us; speedup vs baseline: 2.4211x; 1.6467x over previous
//
#include <hip/hip_runtime.h>

typedef unsigned short u16;
typedef __attribute__((ext_vector_type(4))) float f32x4;
typedef __attribute__((ext_vector_type(8))) short bf16x8;

#define AS1 __attribute__((address_space(1)))
#define AS3 __attribute__((address_space(3)))

__device__ __forceinline__ float bf2f(u16 u) {
  union { unsigned int i; float f; } v; v.i = ((unsigned int)u) << 16; return v.f;
}
__device__ __forceinline__ u16 f2bf(float f) {
  union { float f; unsigned int i; } v; v.f = f;
  unsigned int r = v.i + 0x7fffu + ((v.i >> 16) & 1u);  // RNE
  return (u16)(r >> 16);
}
__device__ __forceinline__ void gload16(const void* g, void* l) {
  __builtin_amdgcn_global_load_lds((const AS1 unsigned int*)g, (AS3 unsigned int*)l, 16, 0, 0);
}

struct GemmDesc {
  const u16* A;      // [M][K] bf16, row stride lda
  const u16* Bt;     // [N][K] bf16, row stride ldb (B transposed)
  const float* Fadd; // optional f32 [M][N] addend (row stride ldd)
  u16* D;            // optional bf16 out, row stride ldd
  u16* Dt;           // optional bf16 transposed out [N][M], row stride lddt
  float* Df;         // optional f32 out, row stride ldd
  int M, N, K, lda, ldb, ldd, lddt, tn, tiles;
  float scale;
};
struct GemmBatch { GemmDesc d[4]; int nd; };

template<int BM, int BN, int FM, int FN>
__device__ __forceinline__ void epilogue(const GemmDesc& d, f32x4 (&acc)[FM][FN],
                                         int m0, int n0, int wm, int wn, int lane) {
  const int r4 = (lane >> 4) << 2;
  const int cc = lane & 15;
  #pragma unroll
  for (int i = 0; i < FM; ++i) {
    #pragma unroll
    for (int j = 0; j < FN; ++j) {
      const int row0 = m0 + wm * (BM / 2) + i * 16 + r4;
      const int col = n0 + wn * (BN / 2) + j * 16 + cc;
      float v[4];
      #pragma unroll
      for (int q = 0; q < 4; ++q) v[q] = acc[i][j][q];
      if (d.Fadd) {
        #pragma unroll
        for (int q = 0; q < 4; ++q) v[q] += d.Fadd[(size_t)(row0 + q) * d.ldd + col];
      }
      if (d.scale != 1.0f) {
        #pragma unroll
        for (int q = 0; q < 4; ++q) v[q] *= d.scale;
      }
      if (d.D) {
        #pragma unroll
        for (int q = 0; q < 4; ++q) d.D[(size_t)(row0 + q) * d.ldd + col] = f2bf(v[q]);
      }
      if (d.Df) {
        #pragma unroll
        for (int q = 0; q < 4; ++q) d.Df[(size_t)(row0 + q) * d.ldd + col] = v[q];
      }
      if (d.Dt) {
        ushort4 pk = make_ushort4(f2bf(v[0]), f2bf(v[1]), f2bf(v[2]), f2bf(v[3]));
        *(ushort4*)&d.Dt[(size_t)col * d.lddt + row0] = pk;
      }
    }
  }
}

// ---------- double-buffered pipelined kernel with T2 XOR-swizzled LDS ----------
// LDS[r][c] holds global[r][c ^ ((r&7)<<3)]; linear LDS dest (gload16), pre-
// swizzled global source col, swizzled read col. 16-way conflict -> 2-way (free).
template<int BM, int BN>
__global__ __launch_bounds__(256) void gemm_db(GemmBatch b) {
  const int nwg = gridDim.x;  // multiple of 8
  int t = ((blockIdx.x & 7) * (nwg >> 3)) + (blockIdx.x >> 3);
  int di = 0;
  while (di + 1 < b.nd && t >= b.d[di].tiles) { t -= b.d[di].tiles; ++di; }
  const GemmDesc d = b.d[di];
  const int tm = t / d.tn, tnn = t - tm * d.tn;
  const int m0 = tm * BM, n0 = tnn * BN;
  const int lane = threadIdx.x & 63;
  const int w = threadIdx.x >> 6;
  const int wm = w >> 1, wn = w & 1;
  constexpr int FM = BM / 32, FN = BN / 32;
  constexpr int HB = (BM + BN) * 64;       // u16 elems per half
  constexpr int L = (BM + BN) / 32;        // gload16 per wave per tile
  __shared__ __align__(16) u16 lds[2 * HB];
  f32x4 acc[FM][FN];
  #pragma unroll
  for (int i = 0; i < FM; ++i)
    #pragma unroll
    for (int j = 0; j < FN; ++j)
      acc[i][j] = (f32x4){0.f, 0.f, 0.f, 0.f};
  const int srow = lane >> 3;
  const int scolz = (((lane & 7) << 3) ^ (srow << 3));  // pre-swizzled source col
  const int rsw = (lane & 7) << 3;                      // read-side XOR constant
  const int nt = d.K / 64;

  auto stagef = [&](int tt, int half) {
    const int k0 = tt * 64;
    u16* base = &lds[half * HB];
    #pragma unroll
    for (int c = w; c < BM / 8; c += 4)
      gload16(d.A + (size_t)(m0 + c * 8 + srow) * d.lda + k0 + scolz, base + c * 512);
    #pragma unroll
    for (int c = w; c < BN / 8; c += 4)
      gload16(d.Bt + (size_t)(n0 + c * 8 + srow) * d.ldb + k0 + scolz, base + BM * 64 + c * 512);
  };

  // prologue: 2-deep prefetch (K >= 128 in all uses)
  stagef(0, 0);
  stagef(1, 1);
  __builtin_amdgcn_sched_barrier(0);
  asm volatile("s_waitcnt vmcnt(%0)" :: "n"(L));  // tile0 landed (ours)
  __builtin_amdgcn_s_barrier();                   // everyone's tile0 landed
  __builtin_amdgcn_sched_barrier(0);

  for (int tt = 0; tt < nt; ++tt) {
    const u16* base = &lds[(tt & 1) * HB];
    #pragma unroll
    for (int kk = 0; kk < 64; kk += 32) {
      const int cb = (kk + ((lane >> 4) << 3)) ^ rsw;  // swizzled col base
      bf16x8 af[FM], bfr[FN];
      #pragma unroll
      for (int i = 0; i < FM; ++i)
        af[i] = *(const bf16x8*)&base[(wm * (BM / 2) + i * 16 + (lane & 15)) * 64 + cb];
      #pragma unroll
      for (int j = 0; j < FN; ++j)
        bfr[j] = *(const bf16x8*)&base[BM * 64 + (wn * (BN / 2) + j * 16 + (lane & 15)) * 64 + cb];
      #pragma unroll
      for (int i = 0; i < FM; ++i)
        #pragma unroll
        for (int j = 0; j < FN; ++j)
          acc[i][j] = __builtin_amdgcn_mfma_f32_16x16x32_bf16(af[i], bfr[j], acc[i][j], 0, 0, 0);
    }
    if (tt + 1 < nt) {
      __builtin_amdgcn_s_barrier();      // all waves done reading buf[tt&1]
      __builtin_amdgcn_sched_barrier(0);
      if (tt + 2 < nt) {
        stagef(tt + 2, tt & 1);          // refill freed buffer; loads fly across barrier
        __builtin_amdgcn_sched_barrier(0);
        asm volatile("s_waitcnt vmcnt(%0)" :: "n"(L));  // tile tt+1 landed; tt+2 in flight
      } else {
        asm volatile("s_waitcnt vmcnt(0)");
      }
      __builtin_amdgcn_s_barrier();      // everyone's tile tt+1 landed
      __builtin_amdgcn_sched_barrier(0);
    }
  }
  epilogue<BM, BN, FM, FN>(d, acc, m0, n0, wm, wn, lane);
}

// read f32 [R][C]; write straight bf16 [R][C] and transposed bf16 [C][R] (row stride ldt)
__global__ __launch_bounds__(256) void conv_both(const float* in, u16* outs, u16* outt, int R, int C, int ldt) {
  __shared__ float tile[64][65];
  int tiles_c = C >> 6;
  int tr = blockIdx.x / tiles_c;
  int tc = blockIdx.x - tr * tiles_c;
  int r0 = tr << 6, c0 = tc << 6;
  int lr = threadIdx.x >> 6, lc = threadIdx.x & 63;
  #pragma unroll
  for (int p = 0; p < 16; ++p) {
    int r = p * 4 + lr;
    float v = in[(size_t)(r0 + r) * C + c0 + lc];
    tile[r][lc] = v;
    outs[(size_t)(r0 + r) * C + c0 + lc] = f2bf(v);
  }
  __syncthreads();
  #pragma unroll
  for (int p = 0; p < 16; ++p) {
    int r = p * 4 + lr;
    outt[(size_t)(c0 + r) * ldt + r0 + lc] = f2bf(tile[lc][r]);
  }
}

// transposed-only bf16 convert: out [C][R]
__global__ __launch_bounds__(256) void conv_t(const float* in, u16* out, int R, int C) {
  __shared__ float tile[64][65];
  int tiles_c = C >> 6;
  int tr = blockIdx.x / tiles_c;
  int tc = blockIdx.x - tr * tiles_c;
  int r0 = tr << 6, c0 = tc << 6;
  int lr = threadIdx.x >> 6, lc = threadIdx.x & 63;
  #pragma unroll
  for (int p = 0; p < 16; ++p) {
    int r = p * 4 + lr;
    tile[r][lc] = in[(size_t)(r0 + r) * C + c0 + lc];
  }
  __syncthreads();
  #pragma unroll
  for (int p = 0; p < 16; ++p) {
    int r = p * 4 + lr;
    out[(size_t)(c0 + r) * R + r0 + lc] = f2bf(tile[lc][r]);
  }
}

// f32 -> bf16 straight (n4 = n/4)
__global__ __launch_bounds__(256) void conv_s(const float* in, u16* out, int n4) {
  int idx = blockIdx.x * 256 + threadIdx.x;
  int stride = gridDim.x * 256;
  for (int i = idx; i < n4; i += stride) {
    float4 f = ((const float4*)in)[i];
    ushort4 o = make_ushort4(f2bf(f.x), f2bf(f.y), f2bf(f.z), f2bf(f.w));
    ((ushort4*)out)[i] = o;
  }
}

// t[row] = sum_j KP[row][j], KP bf16 [n][width]; grid = n/4 blocks
__global__ __launch_bounds__(256) void rowsum_bf(const u16* KP, float* t, int width) {
  int w = threadIdx.x >> 6, lane = threadIdx.x & 63;
  int row = blockIdx.x * 4 + w;
  float s = 0.f;
  for (int k0 = lane * 8; k0 < width; k0 += 512) {
    bf16x8 mv = *(const bf16x8*)&KP[(size_t)row * width + k0];
    #pragma unroll
    for (int e = 0; e < 8; ++e) s += bf2f((u16)mv[e]);
  }
  #pragma unroll
  for (int off = 32; off > 0; off >>= 1) s += __shfl_down(s, off);
  if (lane == 0) t[row] = s;
}

// fused: u[row] = dot(C_row, t); D_hat[row][:] = 0.5*(1-u)/512 + 0.5*DF[row][:]
__global__ __launch_bounds__(256) void matvec_dhat(const float* Cm, const float* t,
                                                   const float* DF, float* out) {
  __shared__ float ts[2048];
  for (int i = threadIdx.x; i < 2048; i += 256) ts[i] = t[i];
  __syncthreads();
  int w = threadIdx.x >> 6, lane = threadIdx.x & 63;
  int row = blockIdx.x * 4 + w;
  float s = 0.f;
  for (int k0 = lane * 4; k0 < 2048; k0 += 256) {
    float4 c4 = *(const float4*)&Cm[(size_t)row * 2048 + k0];
    s += c4.x * ts[k0] + c4.y * ts[k0 + 1] + c4.z * ts[k0 + 2] + c4.w * ts[k0 + 3];
  }
  #pragma unroll
  for (int off = 32; off > 0; off >>= 1) s += __shfl_down(s, off);
  s = __shfl(s, 0);
  float coef = 0.5f * (1.0f - s) * (1.0f / 512.0f);
  int j = lane * 8;
  #pragma unroll
  for (int e = 0; e < 8; ++e)
    out[(size_t)row * 512 + j + e] = coef + 0.5f * DF[(size_t)row * 512 + j + e];
}

extern "C" void kernel_launch(void* const* d_in, const int* in_sizes, int n_in,
                              void* d_out, int out_size, void* d_ws, size_t ws_size,
                              hipStream_t stream) {
  (void)in_sizes; (void)n_in; (void)out_size; (void)ws_size;
  const float* Cf  = (const float*)d_in[0];  // [512][2048]
  const float* Af  = (const float*)d_in[1];  // [2048][2048]
  const float* AFf = (const float*)d_in[2];  // [2048][2048]
  const float* BFf = (const float*)d_in[3];  // [2048][512]
  const float* CFf = (const float*)d_in[4];  // [512][2048]
  const float* DFf = (const float*)d_in[5];  // [512][512]
  float* out = (float*)d_out;                // B_hat [2048][512] ++ D_hat [512][512]

  const size_t NN = 2048ull * 2048ull;
  const size_t SK = 512ull * 2048ull;        // skinny panel elems
  char* ws = (char*)d_ws;
  u16* Mb   = (u16*)ws;            // M = A^T straight [2048][2048]
  u16* Nb   = Mb + NN;             // N = A_F straight [2048][2048]
  u16* KP   = Nb + NN;             // [P0|P1|P2|P3] [2048][2048], P_k = M^k C^T
  u16* Cb   = KP + NN;             // C straight [512][2048] (= P0^T)
  u16* P1T  = Cb + SK;             // P1^T [512][2048]
  u16* P2T  = P1T + SK;            // P2^T
  u16* BFT  = P2T + SK;            // B_F^T = e0^T [512][2048]
  u16* E1T  = BFT + SK;            // e1^T
  u16* E2T  = E1T + SK;            // e2^T
  u16* E3T  = E2T + SK;            // e3^T
  u16* WB   = E3T + SK;            // [w0^T|w1^T|w2^T|w3^T] [512][2048]
  u16* CFb  = WB + SK;             // C_F straight [512][2048]
  float* Vf = (float*)(CFb + SK);  // partA f32 [2048][512]
  float* tv = Vf + 2048ull * 512;  // t [2048]

  auto mk = [](const u16* A, int lda, const u16* Bt, int ldb, const float* Fadd,
               u16* D, u16* Dt, float* Df, int ldd, int lddt,
               int M, int N, int K, float scale, int bm, int bn) {
    GemmDesc g; g.A = A; g.Bt = Bt; g.Fadd = Fadd; g.D = D; g.Dt = Dt; g.Df = Df;
    g.M = M; g.N = N; g.K = K; g.lda = lda; g.ldb = ldb; g.ldd = ldd; g.lddt = lddt;
    g.tn = N / bn; g.tiles = (M / bm) * (N / bn); g.scale = scale; return g;
  };

  // ---- conversions (M,N single-form only) ----
  conv_t<<<1024, 256, 0, stream>>>(Af, Mb, 2048, 2048);               // Mb = A^T = M
  conv_s<<<1024, 256, 0, stream>>>(AFf, Nb, NN / 4);                  // Nb = A_F = N
  conv_both<<<256, 256, 0, stream>>>(Cf, Cb, KP, 512, 2048, 2048);    // Cb = C; KP block0 = C^T
  conv_t<<<256, 256, 0, stream>>>(BFf, BFT, 2048, 512);               // BFT = B_F^T (e0^T)
  conv_s<<<512, 256, 0, stream>>>(CFf, CFb, SK / 4);                  // CFb = C_F

  // ---- G1: P1 = M@P0 (D->KP+512, Dt->P1T) | e1 = N@e0 (Dt->E1T) | w0 = C_F@e0 (Dt->WB) ----
  { GemmBatch gb{}; gb.nd = 3;
    gb.d[0] = mk(Mb, 2048, Cb, 2048, nullptr, KP + 512, P1T, nullptr, 2048, 2048, 2048, 512, 2048, 1.f, 128, 64);
    gb.d[1] = mk(Nb, 2048, BFT, 2048, nullptr, nullptr, E1T, nullptr, 0, 2048, 2048, 512, 2048, 1.f, 128, 64);
    gb.d[2] = mk(CFb, 2048, BFT, 2048, nullptr, nullptr, WB, nullptr, 0, 2048, 512, 512, 2048, 1.f, 128, 64);
    gemm_db<128, 64><<<288, 256, 0, stream>>>(gb); }

  // ---- G2: P2 = M@P1 (D->KP+1024, Dt->P2T) | e2 = N@e1 (Dt->E2T) | w1 = C_F@e1 (Dt->WB+512) ----
  { GemmBatch gb{}; gb.nd = 3;
    gb.d[0] = mk(Mb, 2048, P1T, 2048, nullptr, KP + 1024, P2T, nullptr, 2048, 2048, 2048, 512, 2048, 1.f, 128, 64);
    gb.d[1] = mk(Nb, 2048, E1T, 2048, nullptr, nullptr, E2T, nullptr, 0, 2048, 2048, 512, 2048, 1.f, 128, 64);
    gb.d[2] = mk(CFb, 2048, E1T, 2048, nullptr, nullptr, WB + 512, nullptr, 0, 2048, 512, 512, 2048, 1.f, 128, 64);
    gemm_db<128, 64><<<288, 256, 0, stream>>>(gb); }

  // ---- G3: P3 = M@P2 (D->KP+1536) | e3 = N@e2 (Dt->E3T) | w2 = C_F@e2 (Dt->WB+1024) ----
  { GemmBatch gb{}; gb.nd = 3;
    gb.d[0] = mk(Mb, 2048, P2T, 2048, nullptr, KP + 1536, nullptr, nullptr, 2048, 0, 2048, 512, 2048, 1.f, 128, 64);
    gb.d[1] = mk(Nb, 2048, E2T, 2048, nullptr, nullptr, E3T, nullptr, 0, 2048, 2048, 512, 2048, 1.f, 128, 64);
    gb.d[2] = mk(CFb, 2048, E2T, 2048, nullptr, nullptr, WB + 1024, nullptr, 0, 2048, 512, 512, 2048, 1.f, 128, 64);
    gemm_db<128, 64><<<288, 256, 0, stream>>>(gb); }

  // ---- G4: w3 = C_F@e3 (Dt->WB+1536) | partA = KP[:,0:1536]@WB[:,0:1536]^T (f32 Vf, K=1536) ----
  { GemmBatch gb{}; gb.nd = 2;
    gb.d[0] = mk(CFb, 2048, E3T, 2048, nullptr, nullptr, WB + 1536, nullptr, 0, 2048, 512, 512, 2048, 1.f, 128, 64);
    gb.d[1] = mk(KP, 2048, WB, 2048, nullptr, nullptr, nullptr, Vf, 512, 0, 2048, 512, 1536, 1.f, 128, 64);
    gemm_db<128, 64><<<160, 256, 0, stream>>>(gb); }

  // ---- G5: B_hat = -(partA + P3@w3) -> d_out f32 (K=512) ----
  { GemmBatch gb{}; gb.nd = 1;
    gb.d[0] = mk(KP + 1536, 2048, WB + 1536, 2048, Vf, nullptr, nullptr, out, 512, 0, 2048, 512, 512, -1.f, 128, 64);
    gemm_db<128, 64><<<128, 256, 0, stream>>>(gb); }

  // ---- D_hat: t = rowsum(KP) = sum_{k<4} M^k C^T 1 ; u = C t ; D_hat fused ----
  rowsum_bf<<<512, 256, 0, stream>>>(KP, tv, 2048);
  matvec_dhat<<<128, 256, 0, stream>>>(Cf, tv, DFf, out + 2048 * 512);
}

// Round 10
// 136.738 us; speedup vs baseline: 2.4814x; 1.0249x over previous
//
#include <hip/hip_runtime.h>

typedef unsigned short u16;
typedef __attribute__((ext_vector_type(4))) float f32x4;
typedef __attribute__((ext_vector_type(8))) short bf16x8;

#define AS1 __attribute__((address_space(1)))
#define AS3 __attribute__((address_space(3)))

__device__ __forceinline__ float bf2f(u16 u) {
  union { unsigned int i; float f; } v; v.i = ((unsigned int)u) << 16; return v.f;
}
__device__ __forceinline__ u16 f2bf(float f) {
  union { float f; unsigned int i; } v; v.f = f;
  unsigned int r = v.i + 0x7fffu + ((v.i >> 16) & 1u);  // RNE
  return (u16)(r >> 16);
}
__device__ __forceinline__ void gload16(const void* g, void* l) {
  __builtin_amdgcn_global_load_lds((const AS1 unsigned int*)g, (AS3 unsigned int*)l, 16, 0, 0);
}

struct GemmDesc {
  const u16* A;      // [M][K] bf16, row stride lda
  const u16* Bt;     // [N][K] bf16, row stride ldb (B transposed)
  u16* D;            // optional bf16 out, row stride ldd
  u16* Dt;           // optional bf16 transposed out [N][M], row stride lddt
  float* Df;         // optional f32 out, row stride ldd
  int M, N, K, lda, ldb, ldd, lddt, tn, tiles;
  float scale;
};
struct GemmBatch { GemmDesc d[4]; int nd; };

template<int BM, int BN, int FM, int FN>
__device__ __forceinline__ void epilogue(const GemmDesc& d, f32x4 (&acc)[FM][FN],
                                         int m0, int n0, int wm, int wn, int lane) {
  const int r4 = (lane >> 4) << 2;
  const int cc = lane & 15;
  #pragma unroll
  for (int i = 0; i < FM; ++i) {
    #pragma unroll
    for (int j = 0; j < FN; ++j) {
      const int row0 = m0 + wm * (BM / 2) + i * 16 + r4;
      const int col = n0 + wn * (BN / 2) + j * 16 + cc;
      float v[4];
      #pragma unroll
      for (int q = 0; q < 4; ++q) v[q] = acc[i][j][q];
      if (d.scale != 1.0f) {
        #pragma unroll
        for (int q = 0; q < 4; ++q) v[q] *= d.scale;
      }
      if (d.D) {
        #pragma unroll
        for (int q = 0; q < 4; ++q) d.D[(size_t)(row0 + q) * d.ldd + col] = f2bf(v[q]);
      }
      if (d.Df) {
        #pragma unroll
        for (int q = 0; q < 4; ++q) d.Df[(size_t)(row0 + q) * d.ldd + col] = v[q];
      }
      if (d.Dt) {
        ushort4 pk = make_ushort4(f2bf(v[0]), f2bf(v[1]), f2bf(v[2]), f2bf(v[3]));
        *(ushort4*)&d.Dt[(size_t)col * d.lddt + row0] = pk;
      }
    }
  }
}

// ---------- double-buffered pipelined kernel with T2 XOR-swizzled LDS ----------
template<int BM, int BN>
__global__ __launch_bounds__(256) void gemm_db(GemmBatch b) {
  const int nwg = gridDim.x;  // multiple of 8
  int t = ((blockIdx.x & 7) * (nwg >> 3)) + (blockIdx.x >> 3);
  int di = 0;
  while (di + 1 < b.nd && t >= b.d[di].tiles) { t -= b.d[di].tiles; ++di; }
  const GemmDesc d = b.d[di];
  const int tm = t / d.tn, tnn = t - tm * d.tn;
  const int m0 = tm * BM, n0 = tnn * BN;
  const int lane = threadIdx.x & 63;
  const int w = threadIdx.x >> 6;
  const int wm = w >> 1, wn = w & 1;
  constexpr int FM = BM / 32, FN = BN / 32;
  constexpr int HB = (BM + BN) * 64;       // u16 elems per half
  constexpr int L = (BM + BN) / 32;        // gload16 per wave per tile
  __shared__ __align__(16) u16 lds[2 * HB];
  f32x4 acc[FM][FN];
  #pragma unroll
  for (int i = 0; i < FM; ++i)
    #pragma unroll
    for (int j = 0; j < FN; ++j)
      acc[i][j] = (f32x4){0.f, 0.f, 0.f, 0.f};
  const int srow = lane >> 3;
  const int scolz = (((lane & 7) << 3) ^ (srow << 3));  // pre-swizzled source col
  const int rsw = (lane & 7) << 3;                      // read-side XOR constant
  const int nt = d.K / 64;

  auto stagef = [&](int tt, int half) {
    const int k0 = tt * 64;
    u16* base = &lds[half * HB];
    #pragma unroll
    for (int c = w; c < BM / 8; c += 4)
      gload16(d.A + (size_t)(m0 + c * 8 + srow) * d.lda + k0 + scolz, base + c * 512);
    #pragma unroll
    for (int c = w; c < BN / 8; c += 4)
      gload16(d.Bt + (size_t)(n0 + c * 8 + srow) * d.ldb + k0 + scolz, base + BM * 64 + c * 512);
  };

  // prologue: 2-deep prefetch (K >= 128 in all uses)
  stagef(0, 0);
  stagef(1, 1);
  __builtin_amdgcn_sched_barrier(0);
  asm volatile("s_waitcnt vmcnt(%0)" :: "n"(L));  // tile0 landed (ours)
  __builtin_amdgcn_s_barrier();                   // everyone's tile0 landed
  __builtin_amdgcn_sched_barrier(0);

  for (int tt = 0; tt < nt; ++tt) {
    const u16* base = &lds[(tt & 1) * HB];
    #pragma unroll
    for (int kk = 0; kk < 64; kk += 32) {
      const int cb = (kk + ((lane >> 4) << 3)) ^ rsw;  // swizzled col base
      bf16x8 af[FM], bfr[FN];
      #pragma unroll
      for (int i = 0; i < FM; ++i)
        af[i] = *(const bf16x8*)&base[(wm * (BM / 2) + i * 16 + (lane & 15)) * 64 + cb];
      #pragma unroll
      for (int j = 0; j < FN; ++j)
        bfr[j] = *(const bf16x8*)&base[BM * 64 + (wn * (BN / 2) + j * 16 + (lane & 15)) * 64 + cb];
      #pragma unroll
      for (int i = 0; i < FM; ++i)
        #pragma unroll
        for (int j = 0; j < FN; ++j)
          acc[i][j] = __builtin_amdgcn_mfma_f32_16x16x32_bf16(af[i], bfr[j], acc[i][j], 0, 0, 0);
    }
    if (tt + 1 < nt) {
      __builtin_amdgcn_s_barrier();      // all waves done reading buf[tt&1]
      __builtin_amdgcn_sched_barrier(0);
      if (tt + 2 < nt) {
        stagef(tt + 2, tt & 1);          // refill freed buffer; loads fly across barrier
        __builtin_amdgcn_sched_barrier(0);
        asm volatile("s_waitcnt vmcnt(%0)" :: "n"(L));  // tile tt+1 landed; tt+2 in flight
      } else {
        asm volatile("s_waitcnt vmcnt(0)");
      }
      __builtin_amdgcn_s_barrier();      // everyone's tile tt+1 landed
      __builtin_amdgcn_sched_barrier(0);
    }
  }
  epilogue<BM, BN, FM, FN>(d, acc, m0, n0, wm, wn, lane);
}

// read f32 [R][C]; write straight bf16 [R][C] and transposed bf16 [C][R] (row stride ldt)
__global__ __launch_bounds__(256) void conv_both(const float* in, u16* outs, u16* outt, int R, int C, int ldt) {
  __shared__ float tile[64][65];
  int tiles_c = C >> 6;
  int tr = blockIdx.x / tiles_c;
  int tc = blockIdx.x - tr * tiles_c;
  int r0 = tr << 6, c0 = tc << 6;
  int lr = threadIdx.x >> 6, lc = threadIdx.x & 63;
  #pragma unroll
  for (int p = 0; p < 16; ++p) {
    int r = p * 4 + lr;
    float v = in[(size_t)(r0 + r) * C + c0 + lc];
    tile[r][lc] = v;
    outs[(size_t)(r0 + r) * C + c0 + lc] = f2bf(v);
  }
  __syncthreads();
  #pragma unroll
  for (int p = 0; p < 16; ++p) {
    int r = p * 4 + lr;
    outt[(size_t)(c0 + r) * ldt + r0 + lc] = f2bf(tile[lc][r]);
  }
}

// transposed-only bf16 convert: out [C][R]
__global__ __launch_bounds__(256) void conv_t(const float* in, u16* out, int R, int C) {
  __shared__ float tile[64][65];
  int tiles_c = C >> 6;
  int tr = blockIdx.x / tiles_c;
  int tc = blockIdx.x - tr * tiles_c;
  int r0 = tr << 6, c0 = tc << 6;
  int lr = threadIdx.x >> 6, lc = threadIdx.x & 63;
  #pragma unroll
  for (int p = 0; p < 16; ++p) {
    int r = p * 4 + lr;
    tile[r][lc] = in[(size_t)(r0 + r) * C + c0 + lc];
  }
  __syncthreads();
  #pragma unroll
  for (int p = 0; p < 16; ++p) {
    int r = p * 4 + lr;
    out[(size_t)(c0 + r) * R + r0 + lc] = f2bf(tile[lc][r]);
  }
}

// f32 -> bf16 straight (n4 = n/4)
__global__ __launch_bounds__(256) void conv_s(const float* in, u16* out, int n4) {
  int idx = blockIdx.x * 256 + threadIdx.x;
  int stride = gridDim.x * 256;
  for (int i = idx; i < n4; i += stride) {
    float4 f = ((const float4*)in)[i];
    ushort4 o = make_ushort4(f2bf(f.x), f2bf(f.y), f2bf(f.z), f2bf(f.w));
    ((ushort4*)out)[i] = o;
  }
}

// t[row] = sum_j KP[row][j], KP bf16 [n][width]; grid = n/4 blocks
__global__ __launch_bounds__(256) void rowsum_bf(const u16* KP, float* t, int width) {
  int w = threadIdx.x >> 6, lane = threadIdx.x & 63;
  int row = blockIdx.x * 4 + w;
  float s = 0.f;
  for (int k0 = lane * 8; k0 < width; k0 += 512) {
    bf16x8 mv = *(const bf16x8*)&KP[(size_t)row * width + k0];
    #pragma unroll
    for (int e = 0; e < 8; ++e) s += bf2f((u16)mv[e]);
  }
  #pragma unroll
  for (int off = 32; off > 0; off >>= 1) s += __shfl_down(s, off);
  if (lane == 0) t[row] = s;
}

// fused: u[row] = dot(C_row, t); D_hat[row][:] = 0.5*(1-u)/512 + 0.5*DF[row][:]
__global__ __launch_bounds__(256) void matvec_dhat(const float* Cm, const float* t,
                                                   const float* DF, float* out) {
  __shared__ float ts[2048];
  for (int i = threadIdx.x; i < 2048; i += 256) ts[i] = t[i];
  __syncthreads();
  int w = threadIdx.x >> 6, lane = threadIdx.x & 63;
  int row = blockIdx.x * 4 + w;
  float s = 0.f;
  for (int k0 = lane * 4; k0 < 2048; k0 += 256) {
    float4 c4 = *(const float4*)&Cm[(size_t)row * 2048 + k0];
    s += c4.x * ts[k0] + c4.y * ts[k0 + 1] + c4.z * ts[k0 + 2] + c4.w * ts[k0 + 3];
  }
  #pragma unroll
  for (int off = 32; off > 0; off >>= 1) s += __shfl_down(s, off);
  s = __shfl(s, 0);
  float coef = 0.5f * (1.0f - s) * (1.0f / 512.0f);
  int j = lane * 8;
  #pragma unroll
  for (int e = 0; e < 8; ++e)
    out[(size_t)row * 512 + j + e] = coef + 0.5f * DF[(size_t)row * 512 + j + e];
}

extern "C" void kernel_launch(void* const* d_in, const int* in_sizes, int n_in,
                              void* d_out, int out_size, void* d_ws, size_t ws_size,
                              hipStream_t stream) {
  (void)in_sizes; (void)n_in; (void)out_size; (void)ws_size;
  const float* Cf  = (const float*)d_in[0];  // [512][2048]
  const float* Af  = (const float*)d_in[1];  // [2048][2048]
  const float* AFf = (const float*)d_in[2];  // [2048][2048]
  const float* BFf = (const float*)d_in[3];  // [2048][512]
  const float* CFf = (const float*)d_in[4];  // [512][2048]
  const float* DFf = (const float*)d_in[5];  // [512][512]
  float* out = (float*)d_out;                // B_hat [2048][512] ++ D_hat [512][512]

  const size_t NN = 2048ull * 2048ull;
  const size_t SK = 512ull * 2048ull;        // skinny panel elems
  char* ws = (char*)d_ws;
  u16* Mb   = (u16*)ws;            // M = A^T straight [2048][2048]
  u16* Nb   = Mb + NN;             // N = A_F straight [2048][2048]
  u16* KP   = Nb + NN;             // [P0|P1|P2|P3] [2048][2048], P_k = M^k C^T
  u16* Cb   = KP + NN;             // C straight [512][2048] (= P0^T)
  u16* P1T  = Cb + SK;             // P1^T [512][2048]
  u16* P2T  = P1T + SK;            // P2^T
  u16* BFT  = P2T + SK;            // B_F^T = e0^T [512][2048]
  u16* E1T  = BFT + SK;            // e1^T
  u16* E2T  = E1T + SK;            // e2^T
  u16* E3T  = E2T + SK;            // e3^T
  u16* WB   = E3T + SK;            // [w0^T|w1^T|w2^T|w3^T] [512][2048]
  u16* CFb  = WB + SK;             // C_F straight [512][2048]
  float* tv = (float*)(CFb + SK);  // t [2048]

  auto mk = [](const u16* A, int lda, const u16* Bt, int ldb,
               u16* D, u16* Dt, float* Df, int ldd, int lddt,
               int M, int N, int K, float scale, int bm, int bn) {
    GemmDesc g; g.A = A; g.Bt = Bt; g.D = D; g.Dt = Dt; g.Df = Df;
    g.M = M; g.N = N; g.K = K; g.lda = lda; g.ldb = ldb; g.ldd = ldd; g.lddt = lddt;
    g.tn = N / bn; g.tiles = (M / bm) * (N / bn); g.scale = scale; return g;
  };

  // ---- conversions ----
  conv_t<<<1024, 256, 0, stream>>>(Af, Mb, 2048, 2048);               // Mb = A^T = M
  conv_s<<<1024, 256, 0, stream>>>(AFf, Nb, NN / 4);                  // Nb = A_F = N
  conv_both<<<256, 256, 0, stream>>>(Cf, Cb, KP, 512, 2048, 2048);    // Cb = C; KP block0 = C^T
  conv_t<<<256, 256, 0, stream>>>(BFf, BFT, 2048, 512);               // BFT = B_F^T (e0^T)
  conv_s<<<512, 256, 0, stream>>>(CFf, CFb, SK / 4);                  // CFb = C_F

  // ---- G1 (256 WG, 1 block/CU): P1 = M@P0 (D->KP+512, Dt->P1T) | e1 = N@e0 (Dt->E1T) ----
  { GemmBatch gb{}; gb.nd = 2;
    gb.d[0] = mk(Mb, 2048, Cb, 2048, KP + 512, P1T, nullptr, 2048, 2048, 2048, 512, 2048, 1.f, 128, 64);
    gb.d[1] = mk(Nb, 2048, BFT, 2048, nullptr, E1T, nullptr, 0, 2048, 2048, 512, 2048, 1.f, 128, 64);
    gemm_db<128, 64><<<256, 256, 0, stream>>>(gb); }

  // ---- G2 (256 WG): P2 = M@P1 (D->KP+1024, Dt->P2T) | e2 = N@e1 (Dt->E2T) ----
  { GemmBatch gb{}; gb.nd = 2;
    gb.d[0] = mk(Mb, 2048, P1T, 2048, KP + 1024, P2T, nullptr, 2048, 2048, 2048, 512, 2048, 1.f, 128, 64);
    gb.d[1] = mk(Nb, 2048, E1T, 2048, nullptr, E2T, nullptr, 0, 2048, 2048, 512, 2048, 1.f, 128, 64);
    gemm_db<128, 64><<<256, 256, 0, stream>>>(gb); }

  // ---- G3 (256 WG): P3 = M@P2 (D->KP+1536) | e3 = N@e2 (Dt->E3T) ----
  { GemmBatch gb{}; gb.nd = 2;
    gb.d[0] = mk(Mb, 2048, P2T, 2048, KP + 1536, nullptr, nullptr, 2048, 0, 2048, 512, 2048, 1.f, 128, 64);
    gb.d[1] = mk(Nb, 2048, E2T, 2048, nullptr, E3T, nullptr, 0, 2048, 2048, 512, 2048, 1.f, 128, 64);
    gemm_db<128, 64><<<256, 256, 0, stream>>>(gb); }

  // ---- G4 (128 WG): w_k = C_F@e_k (Dt->WB+512k), k = 0..3 ----
  { GemmBatch gb{}; gb.nd = 4;
    gb.d[0] = mk(CFb, 2048, BFT, 2048, nullptr, WB, nullptr, 0, 2048, 512, 512, 2048, 1.f, 128, 64);
    gb.d[1] = mk(CFb, 2048, E1T, 2048, nullptr, WB + 512, nullptr, 0, 2048, 512, 512, 2048, 1.f, 128, 64);
    gb.d[2] = mk(CFb, 2048, E2T, 2048, nullptr, WB + 1024, nullptr, 0, 2048, 512, 512, 2048, 1.f, 128, 64);
    gb.d[3] = mk(CFb, 2048, E3T, 2048, nullptr, WB + 1536, nullptr, 0, 2048, 512, 512, 2048, 1.f, 128, 64);
    gemm_db<128, 64><<<128, 256, 0, stream>>>(gb); }

  // ---- G5 (128 WG): B_hat = -(KP @ WB^T) -> d_out f32, K=2048 ----
  { GemmBatch gb{}; gb.nd = 1;
    gb.d[0] = mk(KP, 2048, WB, 2048, nullptr, nullptr, out, 512, 0, 2048, 512, 2048, -1.f, 128, 64);
    gemm_db<128, 64><<<128, 256, 0, stream>>>(gb); }

  // ---- D_hat: t = rowsum(KP) = sum_{k<4} M^k C^T 1 ; u = C t ; D_hat fused ----
  rowsum_bf<<<512, 256, 0, stream>>>(KP, tv, 2048);
  matvec_dhat<<<128, 256, 0, stream>>>(Cf, tv, DFf, out + 2048 * 512);
}

// Round 11
// 133.153 us; speedup vs baseline: 2.5482x; 1.0269x over previous
//
#include <hip/hip_runtime.h>

typedef unsigned short u16;
typedef __attribute__((ext_vector_type(4))) float f32x4;
typedef __attribute__((ext_vector_type(8))) short bf16x8;

#define AS1 __attribute__((address_space(1)))
#define AS3 __attribute__((address_space(3)))

__device__ __forceinline__ float bf2f(u16 u) {
  union { unsigned int i; float f; } v; v.i = ((unsigned int)u) << 16; return v.f;
}
__device__ __forceinline__ u16 f2bf(float f) {
  union { float f; unsigned int i; } v; v.f = f;
  unsigned int r = v.i + 0x7fffu + ((v.i >> 16) & 1u);  // RNE
  return (u16)(r >> 16);
}
__device__ __forceinline__ void gload16(const void* g, void* l) {
  __builtin_amdgcn_global_load_lds((const AS1 unsigned int*)g, (AS3 unsigned int*)l, 16, 0, 0);
}

struct GemmDesc {
  const u16* A;      // [M][K] bf16, row stride lda
  const u16* Bt;     // [N][K] bf16, row stride ldb (B transposed)
  const float* Fadd; // optional f32 [M][N] addend (row stride ldd)
  u16* D;            // optional bf16 out, row stride ldd
  u16* Dt;           // optional bf16 transposed out [N][M], row stride lddt
  float* Df;         // optional f32 out, row stride ldd
  int M, N, K, lda, ldb, ldd, lddt, tn, tiles;
  float scale;
};
struct GemmBatch { GemmDesc d[4]; int nd; };

template<int BM, int BN, int FM, int FN>
__device__ __forceinline__ void epilogue(const GemmDesc& d, f32x4 (&acc)[FM][FN],
                                         int m0, int n0, int wm, int wn, int lane) {
  const int r4 = (lane >> 4) << 2;
  const int cc = lane & 15;
  #pragma unroll
  for (int i = 0; i < FM; ++i) {
    #pragma unroll
    for (int j = 0; j < FN; ++j) {
      const int row0 = m0 + wm * (BM / 2) + i * 16 + r4;
      const int col = n0 + wn * (BN / 2) + j * 16 + cc;
      float v[4];
      #pragma unroll
      for (int q = 0; q < 4; ++q) v[q] = acc[i][j][q];
      if (d.Fadd) {
        #pragma unroll
        for (int q = 0; q < 4; ++q) v[q] += d.Fadd[(size_t)(row0 + q) * d.ldd + col];
      }
      if (d.scale != 1.0f) {
        #pragma unroll
        for (int q = 0; q < 4; ++q) v[q] *= d.scale;
      }
      if (d.D) {
        #pragma unroll
        for (int q = 0; q < 4; ++q) d.D[(size_t)(row0 + q) * d.ldd + col] = f2bf(v[q]);
      }
      if (d.Df) {
        #pragma unroll
        for (int q = 0; q < 4; ++q) d.Df[(size_t)(row0 + q) * d.ldd + col] = v[q];
      }
      if (d.Dt) {
        ushort4 pk = make_ushort4(f2bf(v[0]), f2bf(v[1]), f2bf(v[2]), f2bf(v[3]));
        *(ushort4*)&d.Dt[(size_t)col * d.lddt + row0] = pk;
      }
    }
  }
}

// ---------- 3-deep double-buffered pipelined kernel, T2 XOR-swizzled LDS ----------
// LDS[r][c] holds global[r][c ^ ((r&7)<<3)]; linear LDS dest (gload16), pre-
// swizzled global source col, swizzled read col. Steady state: 3 tiles in
// flight, vmcnt(2L) -> two compute steps of latency headroom per load.
template<int BM, int BN>
__global__ __launch_bounds__(256) void gemm_db(GemmBatch b) {
  const int nwg = gridDim.x;  // multiple of 8
  int t = ((blockIdx.x & 7) * (nwg >> 3)) + (blockIdx.x >> 3);
  int di = 0;
  while (di + 1 < b.nd && t >= b.d[di].tiles) { t -= b.d[di].tiles; ++di; }
  const GemmDesc d = b.d[di];
  const int tm = t / d.tn, tnn = t - tm * d.tn;
  const int m0 = tm * BM, n0 = tnn * BN;
  const int lane = threadIdx.x & 63;
  const int w = threadIdx.x >> 6;
  const int wm = w >> 1, wn = w & 1;
  constexpr int FM = BM / 32, FN = BN / 32;
  constexpr int HB = (BM + BN) * 64;       // u16 elems per buffer
  constexpr int L = (BM + BN) / 32;        // gload16 per wave per tile
  __shared__ __align__(16) u16 lds[3 * HB];
  f32x4 acc[FM][FN];
  #pragma unroll
  for (int i = 0; i < FM; ++i)
    #pragma unroll
    for (int j = 0; j < FN; ++j)
      acc[i][j] = (f32x4){0.f, 0.f, 0.f, 0.f};
  const int srow = lane >> 3;
  const int scolz = (((lane & 7) << 3) ^ (srow << 3));  // pre-swizzled source col
  const int rsw = (lane & 7) << 3;                      // read-side XOR constant
  const int nt = d.K / 64;

  auto stagef = [&](int tt, int buf) {
    const int k0 = tt * 64;
    u16* base = &lds[buf * HB];
    #pragma unroll
    for (int c = w; c < BM / 8; c += 4)
      gload16(d.A + (size_t)(m0 + c * 8 + srow) * d.lda + k0 + scolz, base + c * 512);
    #pragma unroll
    for (int c = w; c < BN / 8; c += 4)
      gload16(d.Bt + (size_t)(n0 + c * 8 + srow) * d.ldb + k0 + scolz, base + BM * 64 + c * 512);
  };

  // prologue: 3-deep prefetch (nt >= 3 in all uses)
  stagef(0, 0);
  stagef(1, 1);
  stagef(2, 2);
  __builtin_amdgcn_sched_barrier(0);
  asm volatile("s_waitcnt vmcnt(%0)" :: "n"(2 * L));  // tile0 landed (ours)
  __builtin_amdgcn_s_barrier();                       // everyone's tile0 landed
  __builtin_amdgcn_sched_barrier(0);

  int cur = 0;
  for (int tt = 0; tt < nt; ++tt) {
    const u16* base = &lds[cur * HB];
    #pragma unroll
    for (int kk = 0; kk < 64; kk += 32) {
      const int cb = (kk + ((lane >> 4) << 3)) ^ rsw;  // swizzled col base
      bf16x8 af[FM], bfr[FN];
      #pragma unroll
      for (int i = 0; i < FM; ++i)
        af[i] = *(const bf16x8*)&base[(wm * (BM / 2) + i * 16 + (lane & 15)) * 64 + cb];
      #pragma unroll
      for (int j = 0; j < FN; ++j)
        bfr[j] = *(const bf16x8*)&base[BM * 64 + (wn * (BN / 2) + j * 16 + (lane & 15)) * 64 + cb];
      #pragma unroll
      for (int i = 0; i < FM; ++i)
        #pragma unroll
        for (int j = 0; j < FN; ++j)
          acc[i][j] = __builtin_amdgcn_mfma_f32_16x16x32_bf16(af[i], bfr[j], acc[i][j], 0, 0, 0);
    }
    if (tt + 1 < nt) {
      __builtin_amdgcn_s_barrier();      // all waves done reading buf[cur]
      __builtin_amdgcn_sched_barrier(0);
      if (tt + 3 < nt) {
        stagef(tt + 3, cur);             // refill freed buffer; loads fly across barrier
        __builtin_amdgcn_sched_barrier(0);
        asm volatile("s_waitcnt vmcnt(%0)" :: "n"(2 * L));  // tile tt+1 landed
      } else if (tt + 2 < nt) {
        asm volatile("s_waitcnt vmcnt(%0)" :: "n"(L));      // tile tt+1 landed; tt+2 in flight
      } else {
        asm volatile("s_waitcnt vmcnt(0)");
      }
      __builtin_amdgcn_s_barrier();      // everyone's tile tt+1 landed
      __builtin_amdgcn_sched_barrier(0);
    }
    cur = (cur == 2) ? 0 : cur + 1;
  }
  epilogue<BM, BN, FM, FN>(d, acc, m0, n0, wm, wn, lane);
}

// ---------- one fused conversion kernel: 2176 blocks, branch by range ----------
__global__ __launch_bounds__(256) void conv_all(const float* Af, const float* AFf,
                                                const float* Cf, const float* BFf,
                                                const float* CFf,
                                                u16* Mb, u16* Nb, u16* Cb, u16* KP,
                                                u16* BFT, u16* CFb) {
  __shared__ float tile[64][65];
  const int b = blockIdx.x, tid = threadIdx.x;
  const int lr = tid >> 6, lc = tid & 63;
  if (b < 1024) {
    // Mb = A^T ; A [2048][2048]
    int tr = b >> 5, tc = b & 31;
    int r0 = tr << 6, c0 = tc << 6;
    #pragma unroll
    for (int p = 0; p < 16; ++p) {
      int r = p * 4 + lr;
      tile[r][lc] = Af[(size_t)(r0 + r) * 2048 + c0 + lc];
    }
    __syncthreads();
    #pragma unroll
    for (int p = 0; p < 16; ++p) {
      int r = p * 4 + lr;
      Mb[(size_t)(c0 + r) * 2048 + r0 + lc] = f2bf(tile[lc][r]);
    }
  } else if (b < 1536) {
    // Nb = A_F straight (512 blocks grid-stride)
    const int n4 = (2048 * 2048) / 4;
    for (int i = (b - 1024) * 256 + tid; i < n4; i += 512 * 256) {
      float4 f = ((const float4*)AFf)[i];
      ((ushort4*)Nb)[i] = make_ushort4(f2bf(f.x), f2bf(f.y), f2bf(f.z), f2bf(f.w));
    }
  } else if (b < 1792) {
    // Cb = C straight ; KP cols 0-511 = C^T ; C [512][2048]
    int bb = b - 1536;
    int tr = bb >> 5, tc = bb & 31;
    int r0 = tr << 6, c0 = tc << 6;
    #pragma unroll
    for (int p = 0; p < 16; ++p) {
      int r = p * 4 + lr;
      float v = Cf[(size_t)(r0 + r) * 2048 + c0 + lc];
      tile[r][lc] = v;
      Cb[(size_t)(r0 + r) * 2048 + c0 + lc] = f2bf(v);
    }
    __syncthreads();
    #pragma unroll
    for (int p = 0; p < 16; ++p) {
      int r = p * 4 + lr;
      KP[(size_t)(c0 + r) * 2048 + r0 + lc] = f2bf(tile[lc][r]);
    }
  } else if (b < 2048) {
    // BFT = B_F^T ; B_F [2048][512]
    int bb = b - 1792;
    int tr = bb >> 3, tc = bb & 7;
    int r0 = tr << 6, c0 = tc << 6;
    #pragma unroll
    for (int p = 0; p < 16; ++p) {
      int r = p * 4 + lr;
      tile[r][lc] = BFf[(size_t)(r0 + r) * 512 + c0 + lc];
    }
    __syncthreads();
    #pragma unroll
    for (int p = 0; p < 16; ++p) {
      int r = p * 4 + lr;
      BFT[(size_t)(c0 + r) * 2048 + r0 + lc] = f2bf(tile[lc][r]);
    }
  } else {
    // CFb = C_F straight (128 blocks grid-stride)
    const int n4 = (512 * 2048) / 4;
    for (int i = (b - 2048) * 256 + tid; i < n4; i += 128 * 256) {
      float4 f = ((const float4*)CFf)[i];
      ((ushort4*)CFb)[i] = make_ushort4(f2bf(f.x), f2bf(f.y), f2bf(f.z), f2bf(f.w));
    }
  }
}

// t[row] = sum_j KP[row][j], KP bf16 [n][width]; grid = n/4 blocks
__global__ __launch_bounds__(256) void rowsum_bf(const u16* KP, float* t, int width) {
  int w = threadIdx.x >> 6, lane = threadIdx.x & 63;
  int row = blockIdx.x * 4 + w;
  float s = 0.f;
  for (int k0 = lane * 8; k0 < width; k0 += 512) {
    bf16x8 mv = *(const bf16x8*)&KP[(size_t)row * width + k0];
    #pragma unroll
    for (int e = 0; e < 8; ++e) s += bf2f((u16)mv[e]);
  }
  #pragma unroll
  for (int off = 32; off > 0; off >>= 1) s += __shfl_down(s, off);
  if (lane == 0) t[row] = s;
}

// fused: u[row] = dot(C_row, t); D_hat[row][:] = 0.5*(1-u)/512 + 0.5*DF[row][:]
__global__ __launch_bounds__(256) void matvec_dhat(const float* Cm, const float* t,
                                                   const float* DF, float* out) {
  __shared__ float ts[2048];
  for (int i = threadIdx.x; i < 2048; i += 256) ts[i] = t[i];
  __syncthreads();
  int w = threadIdx.x >> 6, lane = threadIdx.x & 63;
  int row = blockIdx.x * 4 + w;
  float s = 0.f;
  for (int k0 = lane * 4; k0 < 2048; k0 += 256) {
    float4 c4 = *(const float4*)&Cm[(size_t)row * 2048 + k0];
    s += c4.x * ts[k0] + c4.y * ts[k0 + 1] + c4.z * ts[k0 + 2] + c4.w * ts[k0 + 3];
  }
  #pragma unroll
  for (int off = 32; off > 0; off >>= 1) s += __shfl_down(s, off);
  s = __shfl(s, 0);
  float coef = 0.5f * (1.0f - s) * (1.0f / 512.0f);
  int j = lane * 8;
  #pragma unroll
  for (int e = 0; e < 8; ++e)
    out[(size_t)row * 512 + j + e] = coef + 0.5f * DF[(size_t)row * 512 + j + e];
}

extern "C" void kernel_launch(void* const* d_in, const int* in_sizes, int n_in,
                              void* d_out, int out_size, void* d_ws, size_t ws_size,
                              hipStream_t stream) {
  (void)in_sizes; (void)n_in; (void)out_size; (void)ws_size;
  const float* Cf  = (const float*)d_in[0];  // [512][2048]
  const float* Af  = (const float*)d_in[1];  // [2048][2048]
  const float* AFf = (const float*)d_in[2];  // [2048][2048]
  const float* BFf = (const float*)d_in[3];  // [2048][512]
  const float* CFf = (const float*)d_in[4];  // [512][2048]
  const float* DFf = (const float*)d_in[5];  // [512][512]
  float* out = (float*)d_out;                // B_hat [2048][512] ++ D_hat [512][512]

  const size_t NN = 2048ull * 2048ull;
  const size_t SK = 512ull * 2048ull;
  char* ws = (char*)d_ws;
  u16* Mb   = (u16*)ws;            // M = A^T [2048][2048]
  u16* Nb   = Mb + NN;             // N = A_F [2048][2048]
  u16* KP   = Nb + NN;             // [P0|P1|P2|P3] [2048][2048]
  u16* Cb   = KP + NN;             // C [512][2048] (= P0^T)
  u16* P1T  = Cb + SK;             // P1^T
  u16* P2T  = P1T + SK;            // P2^T
  u16* BFT  = P2T + SK;            // B_F^T = e0^T
  u16* E1T  = BFT + SK;            // e1^T
  u16* E2T  = E1T + SK;            // e2^T
  u16* E3T  = E2T + SK;            // e3^T
  u16* WB   = E3T + SK;            // [w0^T|w1^T|w2^T|w3^T] [512][2048]
  u16* CFb  = WB + SK;             // C_F [512][2048]
  float* Vf = (float*)(CFb + SK);  // partA f32 [2048][512]
  float* tv = Vf + 2048ull * 512;  // t [2048]

  auto mk = [](const u16* A, int lda, const u16* Bt, int ldb, const float* Fadd,
               u16* D, u16* Dt, float* Df, int ldd, int lddt,
               int M, int N, int K, float scale, int bm, int bn) {
    GemmDesc g; g.A = A; g.Bt = Bt; g.Fadd = Fadd; g.D = D; g.Dt = Dt; g.Df = Df;
    g.M = M; g.N = N; g.K = K; g.lda = lda; g.ldb = ldb; g.ldd = ldd; g.lddt = lddt;
    g.tn = N / bn; g.tiles = (M / bm) * (N / bn); g.scale = scale; return g;
  };

  // ---- all conversions in one launch ----
  conv_all<<<2176, 256, 0, stream>>>(Af, AFf, Cf, BFf, CFf, Mb, Nb, Cb, KP, BFT, CFb);

  // ---- G1 (288): P1 = M@P0 (D->KP+512, Dt->P1T) | e1 = N@e0 (Dt->E1T) | w0 = C_F@e0 (Dt->WB) ----
  { GemmBatch gb{}; gb.nd = 3;
    gb.d[0] = mk(Mb, 2048, Cb, 2048, nullptr, KP + 512, P1T, nullptr, 2048, 2048, 2048, 512, 2048, 1.f, 128, 64);
    gb.d[1] = mk(Nb, 2048, BFT, 2048, nullptr, nullptr, E1T, nullptr, 0, 2048, 2048, 512, 2048, 1.f, 128, 64);
    gb.d[2] = mk(CFb, 2048, BFT, 2048, nullptr, nullptr, WB, nullptr, 0, 2048, 512, 512, 2048, 1.f, 128, 64);
    gemm_db<128, 64><<<288, 256, 0, stream>>>(gb); }

  // ---- G2 (288): P2 = M@P1 | e2 = N@e1 | w1 = C_F@e1 ----
  { GemmBatch gb{}; gb.nd = 3;
    gb.d[0] = mk(Mb, 2048, P1T, 2048, nullptr, KP + 1024, P2T, nullptr, 2048, 2048, 2048, 512, 2048, 1.f, 128, 64);
    gb.d[1] = mk(Nb, 2048, E1T, 2048, nullptr, nullptr, E2T, nullptr, 0, 2048, 2048, 512, 2048, 1.f, 128, 64);
    gb.d[2] = mk(CFb, 2048, E1T, 2048, nullptr, nullptr, WB + 512, nullptr, 0, 2048, 512, 512, 2048, 1.f, 128, 64);
    gemm_db<128, 64><<<288, 256, 0, stream>>>(gb); }

  // ---- G3 (288): P3 = M@P2 (D->KP+1536) | e3 = N@e2 (Dt->E3T) | w2 = C_F@e2 ----
  { GemmBatch gb{}; gb.nd = 3;
    gb.d[0] = mk(Mb, 2048, P2T, 2048, nullptr, KP + 1536, nullptr, nullptr, 2048, 0, 2048, 512, 2048, 1.f, 128, 64);
    gb.d[1] = mk(Nb, 2048, E2T, 2048, nullptr, nullptr, E3T, nullptr, 0, 2048, 2048, 512, 2048, 1.f, 128, 64);
    gb.d[2] = mk(CFb, 2048, E2T, 2048, nullptr, nullptr, WB + 1024, nullptr, 0, 2048, 512, 512, 2048, 1.f, 128, 64);
    gemm_db<128, 64><<<288, 256, 0, stream>>>(gb); }

  // ---- G4 (160): w3 = C_F@e3 (Dt->WB+1536) | partA = KP[:,0:1536]@WB[:,0:1536]^T (f32 Vf) ----
  { GemmBatch gb{}; gb.nd = 2;
    gb.d[0] = mk(CFb, 2048, E3T, 2048, nullptr, nullptr, WB + 1536, nullptr, 0, 2048, 512, 512, 2048, 1.f, 128, 64);
    gb.d[1] = mk(KP, 2048, WB, 2048, nullptr, nullptr, nullptr, Vf, 512, 0, 2048, 512, 1536, 1.f, 128, 64);
    gemm_db<128, 64><<<160, 256, 0, stream>>>(gb); }

  // ---- G5 (128): B_hat = -(partA + P3@w3^T) -> d_out f32, K=512 ----
  { GemmBatch gb{}; gb.nd = 1;
    gb.d[0] = mk(KP + 1536, 2048, WB + 1536, 2048, Vf, nullptr, nullptr, out, 512, 0, 2048, 512, 512, -1.f, 128, 64);
    gemm_db<128, 64><<<128, 256, 0, stream>>>(gb); }

  // ---- D_hat: t = rowsum(KP) ; u = C t ; D_hat fused ----
  rowsum_bf<<<512, 256, 0, stream>>>(KP, tv, 2048);
  matvec_dhat<<<128, 256, 0, stream>>>(Cf, tv, DFf, out + 2048 * 512);
}